// Round 14
// baseline (690.514 us; speedup 1.0000x reference)
//
#include <hip/hip_runtime.h>

// Problem constants
#define B_ 256
#define T_ 64
#define V_ 10000
#define E_ 512
#define H_ 1024
#define G_ 4096   // 4*H
#define NWG_ 256

typedef __attribute__((ext_vector_type(8))) short short8;
typedef __attribute__((ext_vector_type(4))) float f32x4;

static __device__ __forceinline__ float bf2f(unsigned short u) {
    return __uint_as_float(((unsigned int)u) << 16);
}
static __device__ __forceinline__ unsigned short f2bf(float f) {
    unsigned int i = __float_as_uint(f);
    unsigned int r = (i + 0x7FFFu + ((i >> 16) & 1u)) >> 16;
    return (unsigned short)r;
}
static __device__ __forceinline__ float sigmoid_f(float x) {
    return 1.0f / (1.0f + __expf(-x));
}
static __device__ __forceinline__ float tanh_f(float x) {
    return 1.0f - 2.0f / (__expf(2.0f * x) + 1.0f);
}
// fp8 e4m3 (OCP) conversion via gfx950 packed-convert
static __device__ __forceinline__ unsigned int f2fp8(float f) {
    int pk = __builtin_amdgcn_cvt_pk_fp8_f32(f, f, 0, false);
    return (unsigned int)(pk & 0xFF);
}

// async global->LDS, 16B per lane
static __device__ __forceinline__ void gload16(const void* g, void* l) {
    __builtin_amdgcn_global_load_lds((const __attribute__((address_space(1))) void*)g,
                                     (__attribute__((address_space(3))) void*)l, 16, 0, 0);
}

// --- agent-coherent primitives (proven rounds 4/7/8/13) ---------------------
// 8B coherent load (bypass L1/L2; fabric/L3 coherence point)
#define LD8C(dst, ptr) \
    asm volatile("global_load_dwordx2 %0, %1, off sc0 sc1" : "=v"(dst) : "v"(ptr))
// drain all vmem, then block scheduler motion across (rule #18)
#define DRAIN() do { asm volatile("s_waitcnt vmcnt(0)" ::: "memory"); \
                     __builtin_amdgcn_sched_barrier(0); } while (0)
// 1B coherent store (write-through to fabric)
#define STBYTEC(ptr, val) \
    asm volatile("global_store_byte %0, %1, off sc0 sc1" :: "v"(ptr), "v"(val) : "memory")
// 4B coherent store
#define STDWC(ptr, val) \
    asm volatile("global_store_dword %0, %1, off sc0 sc1" :: "v"(ptr), "v"(val) : "memory")

static __device__ __forceinline__ unsigned ld_u32_cohere(const void* p) {
    unsigned r;
    asm volatile("global_load_dword %0, %1, off sc0 sc1\n\ts_waitcnt vmcnt(0)"
                 : "=v"(r) : "v"(p) : "memory");
    return r;
}

// ---------------------------------------------------------------------------
// fp32 -> bf16 convert
__global__ __launch_bounds__(256) void k_cvt(const float* __restrict__ in,
                                             unsigned short* __restrict__ out, int n4) {
    int i = blockIdx.x * 256 + threadIdx.x;
    if (i >= n4) return;
    float4 v = reinterpret_cast<const float4*>(in)[i];
    uint2 p;
    p.x = (unsigned int)f2bf(v.x) | ((unsigned int)f2bf(v.y) << 16);
    p.y = (unsigned int)f2bf(v.z) | ((unsigned int)f2bf(v.w) << 16);
    reinterpret_cast<uint2*>(out)[i] = p;
}

// ---------------------------------------------------------------------------
// bf16 [n2*2] -> fp8 e4m3 [n2*2] (pairwise packed convert)
__global__ __launch_bounds__(256) void k_cvt8(const unsigned short* __restrict__ in,
                                              unsigned char* __restrict__ out, int n2) {
    int i = blockIdx.x * 256 + threadIdx.x;
    if (i >= n2) return;
    unsigned int p = reinterpret_cast<const unsigned int*>(in)[i];
    float a = bf2f((unsigned short)(p & 0xFFFF));
    float b = bf2f((unsigned short)(p >> 16));
    int pk = __builtin_amdgcn_cvt_pk_fp8_f32(a, b, 0, false);
    reinterpret_cast<unsigned short*>(out)[i] = (unsigned short)(pk & 0xFFFF);
}

// ---------------------------------------------------------------------------
// W[K][N] fp32 -> WT[N][K] bf16
__global__ __launch_bounds__(256) void k_transpose(const float* __restrict__ w,
                                                   unsigned short* __restrict__ wT,
                                                   int K, int N) {
    __shared__ float tile[32][33];
    int nblk = N >> 5;
    int bx = blockIdx.x % nblk;
    int by = blockIdx.x / nblk;
    int lx = threadIdx.x & 31;
    int ly = threadIdx.x >> 5;
    int k0 = by * 32, n0 = bx * 32;
#pragma unroll
    for (int i = 0; i < 32; i += 8)
        tile[ly + i][lx] = w[(size_t)(k0 + ly + i) * N + n0 + lx];
    __syncthreads();
#pragma unroll
    for (int i = 0; i < 32; i += 8)
        wT[(size_t)(n0 + ly + i) * K + k0 + lx] = f2bf(tile[lx][ly + i]);
}

// ---------------------------------------------------------------------------
// xg[B*T][G] = bf16( embed[seq] @ x2h_w + x2h_b )   (unchanged from r8)
__global__ __launch_bounds__(256) void k_xg(const int* __restrict__ seq,
                                            const unsigned short* __restrict__ emb,  // [V][E]
                                            const unsigned short* __restrict__ wT,   // [G][E]
                                            const float* __restrict__ bias,          // [G]
                                            unsigned short* __restrict__ xg) {       // [B*T][G]
    const int mt = blockIdx.x & 127;
    const int nt = blockIdx.x >> 7;
    const int tid = threadIdx.x;
    const int w = tid >> 6, l = tid & 63, g = l >> 4, li = l & 15;
    const int wr = w >> 1, wc = w & 1;

    __shared__ unsigned short As[128 * 32];
    __shared__ unsigned short Bs[128 * 32];
    __shared__ int seqv[128];

    if (tid < 128) seqv[tid] = seq[mt * 128 + tid];
    __syncthreads();

    const int r0 = w * 16 + (l >> 2);
    const int kc = (l & 3) * 8;
    const unsigned short* asrc0 = emb + (size_t)seqv[r0] * E_ + kc;
    const unsigned short* asrc1 = emb + (size_t)seqv[r0 + 64] * E_ + kc;
    const unsigned short* bsrc0 = wT + (size_t)(nt * 128 + r0) * E_ + kc;
    const unsigned short* bsrc1 = wT + (size_t)(nt * 128 + r0 + 64) * E_ + kc;
    char* aldsw = (char*)As + w * 1024;
    char* bldsw = (char*)Bs + w * 1024;

    f32x4 acc[4][4] = {};
    for (int k0 = 0; k0 < E_; k0 += 32) {
        gload16(asrc0 + k0, aldsw);
        gload16(asrc1 + k0, aldsw + 4096);
        gload16(bsrc0 + k0, bldsw);
        gload16(bsrc1 + k0, bldsw + 4096);
        __syncthreads();
        short8 af[4], bf[4];
#pragma unroll
        for (int i = 0; i < 4; ++i) {
            af[i] = *(const short8*)(As + (wr * 64 + i * 16 + li) * 32 + g * 8);
            bf[i] = *(const short8*)(Bs + (wc * 64 + i * 16 + li) * 32 + g * 8);
        }
#pragma unroll
        for (int i = 0; i < 4; ++i)
#pragma unroll
            for (int j = 0; j < 4; ++j)
                acc[i][j] = __builtin_amdgcn_mfma_f32_16x16x32_bf16(af[i], bf[j], acc[i][j], 0, 0, 0);
        __syncthreads();
    }

#pragma unroll
    for (int j = 0; j < 4; ++j) {
        const int col = nt * 128 + wc * 64 + j * 16 + li;
        const float bv = bias[col];
#pragma unroll
        for (int i = 0; i < 4; ++i) {
            const int row = mt * 128 + wr * 64 + i * 16 + g * 4;
#pragma unroll
            for (int r = 0; r < 4; ++r)
                xg[(size_t)(row + r) * G_ + col] = f2bf(acc[i][j][r] + bv);
        }
    }
}

// ---------------------------------------------------------------------------
// Persistent LSTM recurrence, cooperative launch (256 WGs = 1/CU).
// Structure = round 13 (fp8 path, 513us). ONE change: the A-fragment
// pipeline is a SINGLE latency exposure — all 32 fp8 A-loads (long A[32],
// 64 VGPRs — affordable only in fp8) issued back-to-back, one DRAIN, then
// all 128 MFMAs uninterrupted. (r13 had 4 DRAIN-exposed round trips; the
// fp8 round's <6% gain despite halved traffic showed latency, not BW,
// dominates the step.)
__global__ __launch_bounds__(256) void k_rnn(const unsigned short* __restrict__ xg,  // [B][T][G] bf16
                                             const unsigned char* __restrict__ wT8,  // [G][H] fp8
                                             const float* __restrict__ bias,         // [G]
                                             const int* __restrict__ seq_len,        // [B]
                                             unsigned char* __restrict__ h80,        // [B][H] fp8
                                             unsigned char* __restrict__ h81,        // [B][H] fp8
                                             unsigned short* __restrict__ hb,        // [B][H] bf16 (final)
                                             float* __restrict__ hs,                 // [B][T][H]
                                             float* __restrict__ cs,                 // [B][T][H]
                                             unsigned int* __restrict__ flags) {     // [NWG_]
    const int wg = blockIdx.x;
    const int rb = wg >> 6, cb = wg & 63;   // rb-group contiguous in wg (r7 fix)
    const int tid = threadIdx.x;
    const int w = tid >> 6, l = tid & 63, g = l >> 4, li = l & 15;

    __shared__ unsigned char Bs8[64 * 1024];  // 64 KB fp8 weights, fragment order

    // stage B once in fragment order: granule gidx = (q*32+kk)*64 + lane holds
    // wT8[(q*1024 + cb*16 + (lane&15))*H + kk*32 + (lane>>4)*8 .. +7]  (8B)
    for (int gi = 0; gi < 32; ++gi) {
        int gidx = gi * 256 + tid;            // 0..8191
        int ls = gidx & 63;
        int frag = gidx >> 6;                 // 0..127
        int kk = frag & 31, q = frag >> 5;
        int col = q * 1024 + cb * 16 + (ls & 15);
        const unsigned char* src = wT8 + (size_t)col * H_ + kk * 32 + (ls >> 4) * 8;
        *(long*)(Bs8 + (size_t)gidx * 8) = *(const long*)src;
    }

    const int hc = cb * 16 + li;
    float bv[4];
#pragma unroll
    for (int q = 0; q < 4; ++q) bv[q] = bias[q * 1024 + hc];
    const int m0 = rb * 64 + w * 16 + g * 4;
    int sl[4];
#pragma unroll
    for (int r = 0; r < 4; ++r) sl[r] = seq_len[m0 + r];
    float creg[4] = {0.f, 0.f, 0.f, 0.f};
    float hreg[4] = {0.f, 0.f, 0.f, 0.f};

    const int arow_i = rb * 64 + w * 16 + li;
    const unsigned char* bbase = Bs8 + l * 8;   // fragment order: lane-linear
    // wave-0 poll target: lane tid covers flag rb*64 + tid
    const unsigned int* fp = flags + (rb << 6) + tid;

    __syncthreads();  // Bs8 ready (block-local)

// issue 8 coherent 8B loads into A[c..c+7]
#define LOADSA(c) do { _Pragma("unroll") \
    for (int p = 0; p < 8; ++p) LD8C(A[(c) + p], arow8 + ((c) + p) * 32); } while (0)

// fragment-order B read: uniform offset (q*32+kk)*512, lane-linear base
#define MFMAS(c) do { _Pragma("unroll") \
    for (int p = 0; p < 8; ++p) { \
        const int kk = (c) + p; \
        _Pragma("unroll") \
        for (int q = 0; q < 4; ++q) { \
            long bfv = *(const long*)(bbase + (((q * 32 + kk)) << 9)); \
            acc[q] = __builtin_amdgcn_mfma_f32_16x16x32_fp8_fp8(A[kk], bfv, acc[q], 0, 0, 0); \
        } } } while (0)

    // prologue: prefetch xg for t=0
    unsigned short xgr[4][4];
#pragma unroll
    for (int r = 0; r < 4; ++r) {
        const size_t xoff = ((size_t)(m0 + r) * T_ + 0) * G_ + hc;
#pragma unroll
        for (int q = 0; q < 4; ++q) xgr[r][q] = xg[xoff + q * 1024];
    }
    asm volatile("" ::: "memory");

    for (int t = 0; t < T_; ++t) {
        const unsigned char* h_in = (t & 1) ? h81 : h80;
        unsigned char* h_out = (t & 1) ? h80 : h81;
        const unsigned char* arow8 = h_in + (size_t)arow_i * H_ + g * 8;

        // A-pipeline: ALL 32 coherent loads issued (max memory parallelism),
        // ONE drain (single latency exposure), then 128 MFMAs uninterrupted.
        f32x4 acc[4] = {};
        long A[32];
        LOADSA(0);
        LOADSA(8);
        LOADSA(16);
        LOADSA(24);
        DRAIN();
        MFMAS(0);
        MFMAS(8);
        MFMAS(16);
        MFMAS(24);

        // pointwise + masked update; lane owns rows m0..m0+3 x col hc
        float hsv[4], csv[4];
#pragma unroll
        for (int r = 0; r < 4; ++r) {
            const int m = m0 + r;
            float ig = sigmoid_f(acc[0][r] + bv[0] + bf2f(xgr[r][0]));
            float fg = sigmoid_f(acc[1][r] + bv[1] + bf2f(xgr[r][1]));
            float gg = tanh_f(acc[2][r] + bv[2] + bf2f(xgr[r][2]));
            float og = sigmoid_f(acc[3][r] + bv[3] + bf2f(xgr[r][3]));
            float cn = fg * creg[r] + ig * gg;
            float hn = og * tanh_f(cn);
            bool valid = t < sl[r];
            if (valid) { creg[r] = cn; hreg[r] = hn; }
            hsv[r] = valid ? hn : 0.0f;
            csv[r] = valid ? cn : 0.0f;
            STBYTEC(h_out + (size_t)m * H_ + hc, f2fp8(hreg[r]));
        }

        // publish h_out (only the 4 coherent fp8 stores pending)
        DRAIN();
        __syncthreads();      // whole WG published
        const unsigned int tp1 = (unsigned int)(t + 1);
        if (tid == 0) {
            STDWC(flags + wg, tp1);
        }

        // off-critical-path: hs/cs outputs for this step
#pragma unroll
        for (int r = 0; r < 4; ++r) {
            const size_t ooff = ((size_t)(m0 + r) * T_ + t) * H_ + hc;
            __builtin_nontemporal_store(hsv[r], &hs[ooff]);
            __builtin_nontemporal_store(csv[r], &cs[ooff]);
        }

        if (t < T_ - 1) {
            // prefetch next step's xg under the barrier wait
#pragma unroll
            for (int r = 0; r < 4; ++r) {
                const size_t xoff = ((size_t)(m0 + r) * T_ + (t + 1)) * G_ + hc;
#pragma unroll
                for (int q = 0; q < 4; ++q) xgr[r][q] = xg[xoff + q * 1024];
            }
            asm volatile("" ::: "memory");
            if (tid < 64) {   // lane i waits for producer WG rb*64+i
                while (ld_u32_cohere(fp) < tp1) __builtin_amdgcn_s_sleep(1);
            }
            __syncthreads();
        }
    }
#undef LOADSA
#undef MFMAS

    // final bf16 h for k_final (exact fp32 state, written once)
#pragma unroll
    for (int r = 0; r < 4; ++r)
        hb[(size_t)(m0 + r) * H_ + hc] = f2bf(hreg[r]);
}

// ---------------------------------------------------------------------------
// final_hidden[B][H] = tanh(h_last @ aff_w + aff_b)   (unchanged)
__global__ __launch_bounds__(256) void k_final(const unsigned short* __restrict__ h,
                                               const unsigned short* __restrict__ wT,
                                               const float* __restrict__ bias,
                                               float* __restrict__ fin) {
    const int rb = blockIdx.x & 3;
    const int nb = blockIdx.x >> 2;
    const int tid = threadIdx.x;
    const int w = tid >> 6;
    const int l = tid & 63;
    const int g = l >> 4, li = l & 15;

    __shared__ unsigned short As[64][40];
    __shared__ unsigned short Bs[64][40];

    const int srow = tid >> 2;
    const int scol = (tid & 3) * 8;
    const unsigned short* aptr = h + (size_t)(rb * 64 + srow) * H_ + scol;
    const unsigned short* bptr = wT + (size_t)(nb * 64 + srow) * H_ + scol;

    f32x4 acc[4] = {};
    int4 ra = *(const int4*)aptr;
    int4 rb2 = *(const int4*)bptr;
    for (int kk = 0; kk < H_; kk += 32) {
        *(int4*)&As[srow][scol] = ra;
        *(int4*)&Bs[srow][scol] = rb2;
        __syncthreads();
        if (kk + 32 < H_) {
            ra = *(const int4*)(aptr + kk + 32);
            rb2 = *(const int4*)(bptr + kk + 32);
        }
        short8 af = *(const short8*)&As[w * 16 + li][g * 8];
#pragma unroll
        for (int q = 0; q < 4; ++q) {
            short8 bf = *(const short8*)&Bs[q * 16 + li][g * 8];
            acc[q] = __builtin_amdgcn_mfma_f32_16x16x32_bf16(af, bf, acc[q], 0, 0, 0);
        }
        __syncthreads();
    }
    const int m0 = rb * 64 + w * 16 + g * 4;
#pragma unroll
    for (int q = 0; q < 4; ++q) {
        int col = nb * 64 + q * 16 + li;
        float bv = bias[col];
#pragma unroll
        for (int r = 0; r < 4; ++r)
            fin[(size_t)(m0 + r) * H_ + col] = tanh_f(acc[q][r] + bv);
    }
}

// ---------------------------------------------------------------------------
__global__ __launch_bounds__(256) void k_mask(const int* __restrict__ seq_len,
                                              float* __restrict__ mask) {
    int i = blockIdx.x * 256 + threadIdx.x;
    int b = i >> 6, t = i & 63;
    mask[i] = (t < seq_len[b]) ? 1.0f : 0.0f;
}

// ---------------------------------------------------------------------------
extern "C" void kernel_launch(void* const* d_in, const int* in_sizes, int n_in,
                              void* d_out, int out_size, void* d_ws, size_t ws_size,
                              hipStream_t stream) {
    const int* seq = (const int*)d_in[0];
    const int* seq_len = (const int*)d_in[1];
    const float* embed = (const float*)d_in[2];
    const float* x2h_w = (const float*)d_in[3];
    const float* x2h_b = (const float*)d_in[4];
    const float* h2h_w = (const float*)d_in[5];
    const float* h2h_b = (const float*)d_in[6];
    const float* aff_w = (const float*)d_in[7];
    const float* aff_b = (const float*)d_in[8];

    float* out = (float*)d_out;
    float* hs = out;
    float* cs = out + (size_t)B_ * T_ * H_;
    float* fin = cs + (size_t)B_ * T_ * H_;
    float* mask = fin + (size_t)B_ * H_;

    char* p = (char*)d_ws;
    unsigned short* emb_b = (unsigned short*)p; p += (size_t)V_ * E_ * 2;
    unsigned short* x2h_t = (unsigned short*)p; p += (size_t)G_ * E_ * 2;
    unsigned short* h2h_t = (unsigned short*)p; p += (size_t)G_ * H_ * 2;
    unsigned char*  h2h_8 = (unsigned char*)p;  p += (size_t)G_ * H_;
    unsigned short* aff_t = (unsigned short*)p; p += (size_t)H_ * H_ * 2;
    unsigned short* xg    = (unsigned short*)p; p += (size_t)B_ * T_ * G_ * 2;
    unsigned char*  h8b0  = (unsigned char*)p;  p += (size_t)B_ * H_;
    unsigned char*  h8b1  = (unsigned char*)p;  p += (size_t)B_ * H_;
    unsigned short* hbuf  = (unsigned short*)p; p += (size_t)B_ * H_ * 2;
    unsigned int*   flags = (unsigned int*)p;   p += NWG_ * sizeof(unsigned int);

    // 1) precompute bf16 operands (+ fp8 h2h weights)
    hipLaunchKernelGGL(k_cvt, dim3((V_ * E_ / 4 + 255) / 256), dim3(256), 0, stream,
                       embed, emb_b, V_ * E_ / 4);
    hipLaunchKernelGGL(k_transpose, dim3((E_ / 32) * (G_ / 32)), dim3(256), 0, stream,
                       x2h_w, x2h_t, E_, G_);
    hipLaunchKernelGGL(k_transpose, dim3((H_ / 32) * (G_ / 32)), dim3(256), 0, stream,
                       h2h_w, h2h_t, H_, G_);
    hipLaunchKernelGGL(k_cvt8, dim3((G_ * H_ / 2 + 255) / 256), dim3(256), 0, stream,
                       h2h_t, h2h_8, G_ * H_ / 2);
    hipLaunchKernelGGL(k_transpose, dim3((H_ / 32) * (H_ / 32)), dim3(256), 0, stream,
                       aff_w, aff_t, H_, H_);

    // 2) xg = embed[seq] @ x2h_w + b
    hipLaunchKernelGGL(k_xg, dim3(128 * 32), dim3(256), 0, stream,
                       seq, emb_b, x2h_t, x2h_b, xg);

    // 3) zero initial fp8 h (ping buffer) + flags (every launch)
    hipMemsetAsync(h8b0, 0, (size_t)B_ * H_, stream);
    hipMemsetAsync(flags, 0, NWG_ * sizeof(unsigned int), stream);

    // 4) persistent cooperative recurrence (fp8 matmul path)
    {
        const unsigned short* xg_p = xg;
        const unsigned char* wT8_p = h2h_8;
        const float* b_p = h2h_b;
        const int* sl_p = seq_len;
        unsigned char* h80_p = h8b0;
        unsigned char* h81_p = h8b1;
        unsigned short* hb_p = hbuf;
        float* hs_p = hs;
        float* cs_p = cs;
        unsigned int* fl_p = flags;
        void* args[] = {(void*)&xg_p, (void*)&wT8_p, (void*)&b_p, (void*)&sl_p,
                        (void*)&h80_p, (void*)&h81_p, (void*)&hb_p,
                        (void*)&hs_p, (void*)&cs_p, (void*)&fl_p};
        hipLaunchCooperativeKernel(reinterpret_cast<void*>(k_rnn), dim3(NWG_), dim3(256),
                                   args, 0, stream);
    }

    // 5) final affine (bf16 h written once by k_rnn epilogue) + mask
    hipLaunchKernelGGL(k_final, dim3(64), dim3(256), 0, stream, hbuf, aff_t, aff_b, fin);
    hipLaunchKernelGGL(k_mask, dim3(B_ * T_ / 256), dim3(256), 0, stream, seq_len, mask);
}

// Round 15
// 612.573 us; speedup vs baseline: 1.1272x; 1.1272x over previous
//
#include <hip/hip_runtime.h>

// Problem constants
#define B_ 256
#define T_ 64
#define V_ 10000
#define E_ 512
#define H_ 1024
#define G_ 4096   // 4*H
#define NWG_ 256

typedef __attribute__((ext_vector_type(8))) short short8;
typedef __attribute__((ext_vector_type(4))) float f32x4;

static __device__ __forceinline__ float bf2f(unsigned short u) {
    return __uint_as_float(((unsigned int)u) << 16);
}
static __device__ __forceinline__ unsigned short f2bf(float f) {
    unsigned int i = __float_as_uint(f);
    unsigned int r = (i + 0x7FFFu + ((i >> 16) & 1u)) >> 16;
    return (unsigned short)r;
}
static __device__ __forceinline__ float sigmoid_f(float x) {
    return 1.0f / (1.0f + __expf(-x));
}
static __device__ __forceinline__ float tanh_f(float x) {
    return 1.0f - 2.0f / (__expf(2.0f * x) + 1.0f);
}
// fp8 e4m3 (OCP) conversion via gfx950 packed-convert
static __device__ __forceinline__ unsigned int f2fp8(float f) {
    int pk = __builtin_amdgcn_cvt_pk_fp8_f32(f, f, 0, false);
    return (unsigned int)(pk & 0xFF);
}

// async global->LDS, 16B per lane
static __device__ __forceinline__ void gload16(const void* g, void* l) {
    __builtin_amdgcn_global_load_lds((const __attribute__((address_space(1))) void*)g,
                                     (__attribute__((address_space(3))) void*)l, 16, 0, 0);
}

// --- agent-coherent primitives (proven rounds 4/7/8/13) ---------------------
// drain all vmem, then block scheduler motion across (rule #18)
#define DRAIN() do { asm volatile("s_waitcnt vmcnt(0)" ::: "memory"); \
                     __builtin_amdgcn_sched_barrier(0); } while (0)
// 1B coherent store (write-through to fabric/L3)
#define STBYTEC(ptr, val) \
    asm volatile("global_store_byte %0, %1, off sc0 sc1" :: "v"(ptr), "v"(val) : "memory")
// 4B coherent store
#define STDWC(ptr, val) \
    asm volatile("global_store_dword %0, %1, off sc0 sc1" :: "v"(ptr), "v"(val) : "memory")

static __device__ __forceinline__ unsigned ld_u32_cohere(const void* p) {
    unsigned r;
    asm volatile("global_load_dword %0, %1, off sc0 sc1\n\ts_waitcnt vmcnt(0)"
                 : "=v"(r) : "v"(p) : "memory");
    return r;
}

// ---------------------------------------------------------------------------
// fp32 -> bf16 convert
__global__ __launch_bounds__(256) void k_cvt(const float* __restrict__ in,
                                             unsigned short* __restrict__ out, int n4) {
    int i = blockIdx.x * 256 + threadIdx.x;
    if (i >= n4) return;
    float4 v = reinterpret_cast<const float4*>(in)[i];
    uint2 p;
    p.x = (unsigned int)f2bf(v.x) | ((unsigned int)f2bf(v.y) << 16);
    p.y = (unsigned int)f2bf(v.z) | ((unsigned int)f2bf(v.w) << 16);
    reinterpret_cast<uint2*>(out)[i] = p;
}

// ---------------------------------------------------------------------------
// W[K][N] fp32 -> WT[N][K] bf16
__global__ __launch_bounds__(256) void k_transpose(const float* __restrict__ w,
                                                   unsigned short* __restrict__ wT,
                                                   int K, int N) {
    __shared__ float tile[32][33];
    int nblk = N >> 5;
    int bx = blockIdx.x % nblk;
    int by = blockIdx.x / nblk;
    int lx = threadIdx.x & 31;
    int ly = threadIdx.x >> 5;
    int k0 = by * 32, n0 = bx * 32;
#pragma unroll
    for (int i = 0; i < 32; i += 8)
        tile[ly + i][lx] = w[(size_t)(k0 + ly + i) * N + n0 + lx];
    __syncthreads();
#pragma unroll
    for (int i = 0; i < 32; i += 8)
        wT[(size_t)(n0 + ly + i) * K + k0 + lx] = f2bf(tile[lx][ly + i]);
}

// ---------------------------------------------------------------------------
// W[K][N] fp32 -> WT[N][K] fp8 e4m3 (direct; replaces bf16 intermediate + cvt8)
__global__ __launch_bounds__(256) void k_transpose8(const float* __restrict__ w,
                                                    unsigned char* __restrict__ wT,
                                                    int K, int N) {
    __shared__ float tile[32][33];
    int nblk = N >> 5;
    int bx = blockIdx.x % nblk;
    int by = blockIdx.x / nblk;
    int lx = threadIdx.x & 31;
    int ly = threadIdx.x >> 5;
    int k0 = by * 32, n0 = bx * 32;
#pragma unroll
    for (int i = 0; i < 32; i += 8)
        tile[ly + i][lx] = w[(size_t)(k0 + ly + i) * N + n0 + lx];
    __syncthreads();
#pragma unroll
    for (int i = 0; i < 32; i += 8)
        wT[(size_t)(n0 + ly + i) * K + k0 + lx] = (unsigned char)f2fp8(tile[lx][ly + i]);
}

// ---------------------------------------------------------------------------
// xg[B*T][G] = bf16( embed[seq] @ x2h_w + x2h_b )   (unchanged from r8)
__global__ __launch_bounds__(256) void k_xg(const int* __restrict__ seq,
                                            const unsigned short* __restrict__ emb,  // [V][E]
                                            const unsigned short* __restrict__ wT,   // [G][E]
                                            const float* __restrict__ bias,          // [G]
                                            unsigned short* __restrict__ xg) {       // [B*T][G]
    const int mt = blockIdx.x & 127;
    const int nt = blockIdx.x >> 7;
    const int tid = threadIdx.x;
    const int w = tid >> 6, l = tid & 63, g = l >> 4, li = l & 15;
    const int wr = w >> 1, wc = w & 1;

    __shared__ unsigned short As[128 * 32];
    __shared__ unsigned short Bs[128 * 32];
    __shared__ int seqv[128];

    if (tid < 128) seqv[tid] = seq[mt * 128 + tid];
    __syncthreads();

    const int r0 = w * 16 + (l >> 2);
    const int kc = (l & 3) * 8;
    const unsigned short* asrc0 = emb + (size_t)seqv[r0] * E_ + kc;
    const unsigned short* asrc1 = emb + (size_t)seqv[r0 + 64] * E_ + kc;
    const unsigned short* bsrc0 = wT + (size_t)(nt * 128 + r0) * E_ + kc;
    const unsigned short* bsrc1 = wT + (size_t)(nt * 128 + r0 + 64) * E_ + kc;
    char* aldsw = (char*)As + w * 1024;
    char* bldsw = (char*)Bs + w * 1024;

    f32x4 acc[4][4] = {};
    for (int k0 = 0; k0 < E_; k0 += 32) {
        gload16(asrc0 + k0, aldsw);
        gload16(asrc1 + k0, aldsw + 4096);
        gload16(bsrc0 + k0, bldsw);
        gload16(bsrc1 + k0, bldsw + 4096);
        __syncthreads();
        short8 af[4], bf[4];
#pragma unroll
        for (int i = 0; i < 4; ++i) {
            af[i] = *(const short8*)(As + (wr * 64 + i * 16 + li) * 32 + g * 8);
            bf[i] = *(const short8*)(Bs + (wc * 64 + i * 16 + li) * 32 + g * 8);
        }
#pragma unroll
        for (int i = 0; i < 4; ++i)
#pragma unroll
            for (int j = 0; j < 4; ++j)
                acc[i][j] = __builtin_amdgcn_mfma_f32_16x16x32_bf16(af[i], bf[j], acc[i][j], 0, 0, 0);
        __syncthreads();
    }

#pragma unroll
    for (int j = 0; j < 4; ++j) {
        const int col = nt * 128 + wc * 64 + j * 16 + li;
        const float bv = bias[col];
#pragma unroll
        for (int i = 0; i < 4; ++i) {
            const int row = mt * 128 + wr * 64 + i * 16 + g * 4;
#pragma unroll
            for (int r = 0; r < 4; ++r)
                xg[(size_t)(row + r) * G_ + col] = f2bf(acc[i][j][r] + bv);
        }
    }
}

// ---------------------------------------------------------------------------
// Persistent LSTM recurrence, cooperative launch (256 WGs = 1/CU).
// Structure = round 13 (fp8, 513us). ONE change: h flows through PER-STEP
// buffers h8[t] (65 x 256KB, addresses never reused) so consumers use PLAIN
// CACHED loads — first toucher per XCD misses to L3 (fresh: producers write
// through with sc0sc1 + DRAIN before the flag), the other ~31 WGs on the XCD
// hit L2. This removes the 2M/step 8B sc-bypass requests that the r8/r13/r14
// data showed to be request-rate-bound at the fabric. Replays are safe:
// deterministic math makes any stale cached line bit-identical.
__global__ __launch_bounds__(256) void k_rnn(const unsigned short* __restrict__ xg,  // [B][T][G] bf16
                                             const unsigned char* __restrict__ wT8,  // [G][H] fp8
                                             const float* __restrict__ bias,         // [G]
                                             const int* __restrict__ seq_len,        // [B]
                                             unsigned char* __restrict__ h8,         // [T+1][B][H] fp8
                                             unsigned short* __restrict__ hb,        // [B][H] bf16 (final)
                                             float* __restrict__ hs,                 // [B][T][H]
                                             float* __restrict__ cs,                 // [B][T][H]
                                             unsigned int* __restrict__ flags) {     // [NWG_]
    const int wg = blockIdx.x;
    const int rb = wg >> 6, cb = wg & 63;   // rb-group contiguous in wg (r7 fix)
    const int tid = threadIdx.x;
    const int w = tid >> 6, l = tid & 63, g = l >> 4, li = l & 15;

    __shared__ unsigned char Bs8[64 * 1024];  // 64 KB fp8 weights, fragment order

    // stage B once in fragment order: granule gidx = (q*32+kk)*64 + lane holds
    // wT8[(q*1024 + cb*16 + (lane&15))*H + kk*32 + (lane>>4)*8 .. +7]  (8B)
    for (int gi = 0; gi < 32; ++gi) {
        int gidx = gi * 256 + tid;            // 0..8191
        int ls = gidx & 63;
        int frag = gidx >> 6;                 // 0..127
        int kk = frag & 31, q = frag >> 5;
        int col = q * 1024 + cb * 16 + (ls & 15);
        const unsigned char* src = wT8 + (size_t)col * H_ + kk * 32 + (ls >> 4) * 8;
        *(long*)(Bs8 + (size_t)gidx * 8) = *(const long*)src;
    }

    const int hc = cb * 16 + li;
    float bv[4];
#pragma unroll
    for (int q = 0; q < 4; ++q) bv[q] = bias[q * 1024 + hc];
    const int m0 = rb * 64 + w * 16 + g * 4;
    int sl[4];
#pragma unroll
    for (int r = 0; r < 4; ++r) sl[r] = seq_len[m0 + r];
    float creg[4] = {0.f, 0.f, 0.f, 0.f};
    float hreg[4] = {0.f, 0.f, 0.f, 0.f};

    const int arow_i = rb * 64 + w * 16 + li;
    const unsigned char* bbase = Bs8 + l * 8;   // fragment order: lane-linear
    // wave-0 poll target: lane tid covers flag rb*64 + tid
    const unsigned int* fp = flags + (rb << 6) + tid;

    __syncthreads();  // Bs8 ready (block-local)

// plain cached 8B loads (L2-broadcast path; addresses unique per step)
#define LOADS(buf, c) do { _Pragma("unroll") \
    for (int p = 0; p < 8; ++p) buf[p] = *(const long*)(arow8 + ((c) + p) * 32); } while (0)

// fragment-order B read: uniform offset (q*32+kk)*512, lane-linear base
#define MFMAS(buf, c) do { _Pragma("unroll") \
    for (int p = 0; p < 8; ++p) { \
        const int kk = (c) + p; \
        _Pragma("unroll") \
        for (int q = 0; q < 4; ++q) { \
            long bfv = *(const long*)(bbase + (((q * 32 + kk)) << 9)); \
            acc[q] = __builtin_amdgcn_mfma_f32_16x16x32_fp8_fp8(buf[p], bfv, acc[q], 0, 0, 0); \
        } } } while (0)

    // prologue: prefetch xg for t=0
    unsigned short xgr[4][4];
#pragma unroll
    for (int r = 0; r < 4; ++r) {
        const size_t xoff = ((size_t)(m0 + r) * T_ + 0) * G_ + hc;
#pragma unroll
        for (int q = 0; q < 4; ++q) xgr[r][q] = xg[xoff + q * 1024];
    }
    asm volatile("" ::: "memory");

    for (int t = 0; t < T_; ++t) {
        const unsigned char* h_in = h8 + (size_t)t * (B_ * H_);
        unsigned char* h_out = (unsigned char*)h8 + (size_t)(t + 1) * (B_ * H_);
        const unsigned char* arow8 = h_in + (size_t)arow_i * H_ + g * 8;

        // A-fragment pipeline: plain cached loads, 8-deep double buffer (r13 schedule)
        f32x4 acc[4] = {};
        long A0[8], A1[8];
        LOADS(A0, 0);
        DRAIN();
        LOADS(A1, 8);
        MFMAS(A0, 0);
        DRAIN();
        LOADS(A0, 16);
        MFMAS(A1, 8);
        DRAIN();
        LOADS(A1, 24);
        MFMAS(A0, 16);
        DRAIN();
        MFMAS(A1, 24);

        // pointwise + masked update; lane owns rows m0..m0+3 x col hc
        float hsv[4], csv[4];
#pragma unroll
        for (int r = 0; r < 4; ++r) {
            const int m = m0 + r;
            float ig = sigmoid_f(acc[0][r] + bv[0] + bf2f(xgr[r][0]));
            float fg = sigmoid_f(acc[1][r] + bv[1] + bf2f(xgr[r][1]));
            float gg = tanh_f(acc[2][r] + bv[2] + bf2f(xgr[r][2]));
            float og = sigmoid_f(acc[3][r] + bv[3] + bf2f(xgr[r][3]));
            float cn = fg * creg[r] + ig * gg;
            float hn = og * tanh_f(cn);
            bool valid = t < sl[r];
            if (valid) { creg[r] = cn; hreg[r] = hn; }
            hsv[r] = valid ? hn : 0.0f;
            csv[r] = valid ? cn : 0.0f;
            STBYTEC(h_out + (size_t)m * H_ + hc, f2fp8(hreg[r]));
        }

        // publish h_out (only the 4 write-through fp8 stores pending)
        DRAIN();
        __syncthreads();      // whole WG published
        const unsigned int tp1 = (unsigned int)(t + 1);
        if (tid == 0) {
            STDWC(flags + wg, tp1);
        }

        // off-critical-path: hs/cs outputs for this step
#pragma unroll
        for (int r = 0; r < 4; ++r) {
            const size_t ooff = ((size_t)(m0 + r) * T_ + t) * H_ + hc;
            __builtin_nontemporal_store(hsv[r], &hs[ooff]);
            __builtin_nontemporal_store(csv[r], &cs[ooff]);
        }

        if (t < T_ - 1) {
            // prefetch next step's xg under the barrier wait
#pragma unroll
            for (int r = 0; r < 4; ++r) {
                const size_t xoff = ((size_t)(m0 + r) * T_ + (t + 1)) * G_ + hc;
#pragma unroll
                for (int q = 0; q < 4; ++q) xgr[r][q] = xg[xoff + q * 1024];
            }
            asm volatile("" ::: "memory");
            if (tid < 64) {   // lane i waits for producer WG rb*64+i
                while (ld_u32_cohere(fp) < tp1) __builtin_amdgcn_s_sleep(1);
            }
            __syncthreads();
        }
    }
#undef LOADS
#undef MFMAS

    // final bf16 h for k_final (exact fp32 state, written once)
#pragma unroll
    for (int r = 0; r < 4; ++r)
        hb[(size_t)(m0 + r) * H_ + hc] = f2bf(hreg[r]);
}

// ---------------------------------------------------------------------------
// final_hidden[B][H] = tanh(h_last @ aff_w + aff_b)   (unchanged)
__global__ __launch_bounds__(256) void k_final(const unsigned short* __restrict__ h,
                                               const unsigned short* __restrict__ wT,
                                               const float* __restrict__ bias,
                                               float* __restrict__ fin) {
    const int rb = blockIdx.x & 3;
    const int nb = blockIdx.x >> 2;
    const int tid = threadIdx.x;
    const int w = tid >> 6;
    const int l = tid & 63;
    const int g = l >> 4, li = l & 15;

    __shared__ unsigned short As[64][40];
    __shared__ unsigned short Bs[64][40];

    const int srow = tid >> 2;
    const int scol = (tid & 3) * 8;
    const unsigned short* aptr = h + (size_t)(rb * 64 + srow) * H_ + scol;
    const unsigned short* bptr = wT + (size_t)(nb * 64 + srow) * H_ + scol;

    f32x4 acc[4] = {};
    int4 ra = *(const int4*)aptr;
    int4 rb2 = *(const int4*)bptr;
    for (int kk = 0; kk < H_; kk += 32) {
        *(int4*)&As[srow][scol] = ra;
        *(int4*)&Bs[srow][scol] = rb2;
        __syncthreads();
        if (kk + 32 < H_) {
            ra = *(const int4*)(aptr + kk + 32);
            rb2 = *(const int4*)(bptr + kk + 32);
        }
        short8 af = *(const short8*)&As[w * 16 + li][g * 8];
#pragma unroll
        for (int q = 0; q < 4; ++q) {
            short8 bf = *(const short8*)&Bs[q * 16 + li][g * 8];
            acc[q] = __builtin_amdgcn_mfma_f32_16x16x32_bf16(af, bf, acc[q], 0, 0, 0);
        }
        __syncthreads();
    }
    const int m0 = rb * 64 + w * 16 + g * 4;
#pragma unroll
    for (int q = 0; q < 4; ++q) {
        int col = nb * 64 + q * 16 + li;
        float bv = bias[col];
#pragma unroll
        for (int r = 0; r < 4; ++r)
            fin[(size_t)(m0 + r) * H_ + col] = tanh_f(acc[q][r] + bv);
    }
}

// ---------------------------------------------------------------------------
__global__ __launch_bounds__(256) void k_mask(const int* __restrict__ seq_len,
                                              float* __restrict__ mask) {
    int i = blockIdx.x * 256 + threadIdx.x;
    int b = i >> 6, t = i & 63;
    mask[i] = (t < seq_len[b]) ? 1.0f : 0.0f;
}

// ---------------------------------------------------------------------------
extern "C" void kernel_launch(void* const* d_in, const int* in_sizes, int n_in,
                              void* d_out, int out_size, void* d_ws, size_t ws_size,
                              hipStream_t stream) {
    const int* seq = (const int*)d_in[0];
    const int* seq_len = (const int*)d_in[1];
    const float* embed = (const float*)d_in[2];
    const float* x2h_w = (const float*)d_in[3];
    const float* x2h_b = (const float*)d_in[4];
    const float* h2h_w = (const float*)d_in[5];
    const float* h2h_b = (const float*)d_in[6];
    const float* aff_w = (const float*)d_in[7];
    const float* aff_b = (const float*)d_in[8];

    float* out = (float*)d_out;
    float* hs = out;
    float* cs = out + (size_t)B_ * T_ * H_;
    float* fin = cs + (size_t)B_ * T_ * H_;
    float* mask = fin + (size_t)B_ * H_;

    char* p = (char*)d_ws;
    unsigned short* emb_b = (unsigned short*)p; p += (size_t)V_ * E_ * 2;
    unsigned short* x2h_t = (unsigned short*)p; p += (size_t)G_ * E_ * 2;
    unsigned char*  h2h_8 = (unsigned char*)p;  p += (size_t)G_ * H_;
    unsigned short* aff_t = (unsigned short*)p; p += (size_t)H_ * H_ * 2;
    unsigned short* xg    = (unsigned short*)p; p += (size_t)B_ * T_ * G_ * 2;
    unsigned char*  h8    = (unsigned char*)p;  p += (size_t)(T_ + 1) * B_ * H_;  // 16.6 MB
    unsigned short* hbuf  = (unsigned short*)p; p += (size_t)B_ * H_ * 2;
    unsigned int*   flags = (unsigned int*)p;   p += NWG_ * sizeof(unsigned int);

    // 1) precompute bf16 operands (+ fp8 h2h weights, direct transpose)
    hipLaunchKernelGGL(k_cvt, dim3((V_ * E_ / 4 + 255) / 256), dim3(256), 0, stream,
                       embed, emb_b, V_ * E_ / 4);
    hipLaunchKernelGGL(k_transpose, dim3((E_ / 32) * (G_ / 32)), dim3(256), 0, stream,
                       x2h_w, x2h_t, E_, G_);
    hipLaunchKernelGGL(k_transpose8, dim3((H_ / 32) * (G_ / 32)), dim3(256), 0, stream,
                       h2h_w, h2h_8, H_, G_);
    hipLaunchKernelGGL(k_transpose, dim3((H_ / 32) * (H_ / 32)), dim3(256), 0, stream,
                       aff_w, aff_t, H_, H_);

    // 2) xg = embed[seq] @ x2h_w + b
    hipLaunchKernelGGL(k_xg, dim3(128 * 32), dim3(256), 0, stream,
                       seq, emb_b, x2h_t, x2h_b, xg);

    // 3) zero h8[0] (t=0 input) + flags (every launch)
    hipMemsetAsync(h8, 0, (size_t)B_ * H_, stream);
    hipMemsetAsync(flags, 0, NWG_ * sizeof(unsigned int), stream);

    // 4) persistent cooperative recurrence (fp8 matmul, per-step h buffers)
    {
        const unsigned short* xg_p = xg;
        const unsigned char* wT8_p = h2h_8;
        const float* b_p = h2h_b;
        const int* sl_p = seq_len;
        unsigned char* h8_p = h8;
        unsigned short* hb_p = hbuf;
        float* hs_p = hs;
        float* cs_p = cs;
        unsigned int* fl_p = flags;
        void* args[] = {(void*)&xg_p, (void*)&wT8_p, (void*)&b_p, (void*)&sl_p,
                        (void*)&h8_p, (void*)&hb_p,
                        (void*)&hs_p, (void*)&cs_p, (void*)&fl_p};
        hipLaunchCooperativeKernel(reinterpret_cast<void*>(k_rnn), dim3(NWG_), dim3(256),
                                   args, 0, stream);
    }

    // 5) final affine (bf16 h written once by k_rnn epilogue) + mask
    hipLaunchKernelGGL(k_final, dim3(64), dim3(256), 0, stream, hbuf, aff_t, aff_b, fin);
    hipLaunchKernelGGL(k_mask, dim3(B_ * T_ / 256), dim3(256), 0, stream, seq_len, mask);
}

// Round 16
// 594.101 us; speedup vs baseline: 1.1623x; 1.0311x over previous
//
#include <hip/hip_runtime.h>

// Problem constants
#define B_ 256
#define T_ 64
#define V_ 10000
#define E_ 512
#define H_ 1024
#define G_ 4096   // 4*H
#define NWG_ 256

typedef __attribute__((ext_vector_type(8))) short short8;
typedef __attribute__((ext_vector_type(4))) float f32x4;

static __device__ __forceinline__ float bf2f(unsigned short u) {
    return __uint_as_float(((unsigned int)u) << 16);
}
static __device__ __forceinline__ unsigned short f2bf(float f) {
    unsigned int i = __float_as_uint(f);
    unsigned int r = (i + 0x7FFFu + ((i >> 16) & 1u)) >> 16;
    return (unsigned short)r;
}
static __device__ __forceinline__ float sigmoid_f(float x) {
    return 1.0f / (1.0f + __expf(-x));
}
static __device__ __forceinline__ float tanh_f(float x) {
    return 1.0f - 2.0f / (__expf(2.0f * x) + 1.0f);
}
// fp8 e4m3 (OCP) conversion via gfx950 packed-convert
static __device__ __forceinline__ unsigned int f2fp8(float f) {
    int pk = __builtin_amdgcn_cvt_pk_fp8_f32(f, f, 0, false);
    return (unsigned int)(pk & 0xFF);
}

// async global->LDS, 16B per lane
static __device__ __forceinline__ void gload16(const void* g, void* l) {
    __builtin_amdgcn_global_load_lds((const __attribute__((address_space(1))) void*)g,
                                     (__attribute__((address_space(3))) void*)l, 16, 0, 0);
}

// --- agent-coherent primitives (proven rounds 4/7/8/13) ---------------------
// drain all vmem, then block scheduler motion across (rule #18)
#define DRAIN() do { asm volatile("s_waitcnt vmcnt(0)" ::: "memory"); \
                     __builtin_amdgcn_sched_barrier(0); } while (0)
// 1B coherent store (write-through to fabric/L3)
#define STBYTEC(ptr, val) \
    asm volatile("global_store_byte %0, %1, off sc0 sc1" :: "v"(ptr), "v"(val) : "memory")
// 4B coherent store
#define STDWC(ptr, val) \
    asm volatile("global_store_dword %0, %1, off sc0 sc1" :: "v"(ptr), "v"(val) : "memory")

static __device__ __forceinline__ unsigned ld_u32_cohere(const void* p) {
    unsigned r;
    asm volatile("global_load_dword %0, %1, off sc0 sc1\n\ts_waitcnt vmcnt(0)"
                 : "=v"(r) : "v"(p) : "memory");
    return r;
}

// ---------------------------------------------------------------------------
// fp32 -> bf16 convert
__global__ __launch_bounds__(256) void k_cvt(const float* __restrict__ in,
                                             unsigned short* __restrict__ out, int n4) {
    int i = blockIdx.x * 256 + threadIdx.x;
    if (i >= n4) return;
    float4 v = reinterpret_cast<const float4*>(in)[i];
    uint2 p;
    p.x = (unsigned int)f2bf(v.x) | ((unsigned int)f2bf(v.y) << 16);
    p.y = (unsigned int)f2bf(v.z) | ((unsigned int)f2bf(v.w) << 16);
    reinterpret_cast<uint2*>(out)[i] = p;
}

// ---------------------------------------------------------------------------
// W[K][N] fp32 -> WT[N][K] bf16
__global__ __launch_bounds__(256) void k_transpose(const float* __restrict__ w,
                                                   unsigned short* __restrict__ wT,
                                                   int K, int N) {
    __shared__ float tile[32][33];
    int nblk = N >> 5;
    int bx = blockIdx.x % nblk;
    int by = blockIdx.x / nblk;
    int lx = threadIdx.x & 31;
    int ly = threadIdx.x >> 5;
    int k0 = by * 32, n0 = bx * 32;
#pragma unroll
    for (int i = 0; i < 32; i += 8)
        tile[ly + i][lx] = w[(size_t)(k0 + ly + i) * N + n0 + lx];
    __syncthreads();
#pragma unroll
    for (int i = 0; i < 32; i += 8)
        wT[(size_t)(n0 + ly + i) * K + k0 + lx] = f2bf(tile[lx][ly + i]);
}

// ---------------------------------------------------------------------------
// W[K][N] fp32 -> WT[N][K] fp8 e4m3 (direct)
__global__ __launch_bounds__(256) void k_transpose8(const float* __restrict__ w,
                                                    unsigned char* __restrict__ wT,
                                                    int K, int N) {
    __shared__ float tile[32][33];
    int nblk = N >> 5;
    int bx = blockIdx.x % nblk;
    int by = blockIdx.x / nblk;
    int lx = threadIdx.x & 31;
    int ly = threadIdx.x >> 5;
    int k0 = by * 32, n0 = bx * 32;
#pragma unroll
    for (int i = 0; i < 32; i += 8)
        tile[ly + i][lx] = w[(size_t)(k0 + ly + i) * N + n0 + lx];
    __syncthreads();
#pragma unroll
    for (int i = 0; i < 32; i += 8)
        wT[(size_t)(n0 + ly + i) * K + k0 + lx] = (unsigned char)f2fp8(tile[lx][ly + i]);
}

// ---------------------------------------------------------------------------
// xg[B*T][G] = bf16( embed[seq] @ x2h_w + x2h_b )
// r16: BK=64 (8 iterations, half the barriers) + XOR-swizzled LDS via
// pre-swizzled global source (m173): gload_lds dest stays linear
// (base + lane*16); lane's SOURCE k-byte = db ^ ((row&7)<<4). Fragment
// reads apply the same XOR -> 16-lane ds_read_b128 groups spread over 8
// distinct 16B slots = 2-way aliasing (free), vs the old layout's 8-way.
__global__ __launch_bounds__(256) void k_xg(const int* __restrict__ seq,
                                            const unsigned short* __restrict__ emb,  // [V][E]
                                            const unsigned short* __restrict__ wT,   // [G][E]
                                            const float* __restrict__ bias,          // [G]
                                            unsigned short* __restrict__ xg) {       // [B*T][G]
    const int mt = blockIdx.x & 127;
    const int nt = blockIdx.x >> 7;
    const int tid = threadIdx.x;
    const int w = tid >> 6, l = tid & 63, g = l >> 4, li = l & 15;
    const int wr = w >> 1, wc = w & 1;

    __shared__ unsigned short As[128 * 64];  // 16 KB
    __shared__ unsigned short Bs[128 * 64];  // 16 KB
    __shared__ int seqv[128];

    if (tid < 128) seqv[tid] = seq[mt * 128 + tid];
    __syncthreads();

    // staging: issue j covers rows (j*4+w)*8 + (l>>3); dest = base + (j*4+w)*1024 + lane*16
    const int lr = l >> 3;                 // row-within-octet = row&7
    const int db = (l & 7) * 16;           // dest byte within 128B row
    const int sbel = (db ^ (lr << 4)) >> 1;  // pre-swizzled source element offset
    const unsigned short* asrc[4];
    const unsigned short* bsrc[4];
    char* adst[4];
    char* bdst[4];
#pragma unroll
    for (int j = 0; j < 4; ++j) {
        const int r = (j * 4 + w) * 8 + lr;
        asrc[j] = emb + (size_t)seqv[r] * E_ + sbel;
        bsrc[j] = wT + (size_t)(nt * 128 + r) * E_ + sbel;
        adst[j] = (char*)As + (j * 4 + w) * 1024;
        bdst[j] = (char*)Bs + (j * 4 + w) * 1024;
    }

    const char* Ab = (const char*)As;
    const char* Bb = (const char*)Bs;
    const int lx = (li & 7) << 4;          // read-side XOR (row&7 == li&7)

    f32x4 acc[4][4] = {};
    for (int k0 = 0; k0 < E_; k0 += 64) {
#pragma unroll
        for (int j = 0; j < 4; ++j) {
            gload16(asrc[j] + k0, adst[j]);
            gload16(bsrc[j] + k0, bdst[j]);
        }
        __syncthreads();  // drains vmcnt -> LDS ready
#pragma unroll
        for (int kc2 = 0; kc2 < 2; ++kc2) {
            const int kb = (kc2 * 64 + g * 16) ^ lx;
            short8 af[4], bf[4];
#pragma unroll
            for (int i = 0; i < 4; ++i) {
                af[i] = *(const short8*)(Ab + (wr * 64 + i * 16 + li) * 128 + kb);
                bf[i] = *(const short8*)(Bb + (wc * 64 + i * 16 + li) * 128 + kb);
            }
#pragma unroll
            for (int i = 0; i < 4; ++i)
#pragma unroll
                for (int j = 0; j < 4; ++j)
                    acc[i][j] = __builtin_amdgcn_mfma_f32_16x16x32_bf16(af[i], bf[j], acc[i][j], 0, 0, 0);
        }
        __syncthreads();  // compute done before next stage overwrites
    }

#pragma unroll
    for (int j = 0; j < 4; ++j) {
        const int col = nt * 128 + wc * 64 + j * 16 + li;
        const float bv = bias[col];
#pragma unroll
        for (int i = 0; i < 4; ++i) {
            const int row = mt * 128 + wr * 64 + i * 16 + g * 4;
#pragma unroll
            for (int r = 0; r < 4; ++r)
                xg[(size_t)(row + r) * G_ + col] = f2bf(acc[i][j][r] + bv);
        }
    }
}

// ---------------------------------------------------------------------------
// Persistent LSTM recurrence, cooperative launch (256 WGs = 1/CU).
// IDENTICAL to round 15 (best passing: 473us): fp8 matmul, per-step h
// buffers (plain cached consumer loads), write-through producers, rb-group
// flag barrier.
__global__ __launch_bounds__(256) void k_rnn(const unsigned short* __restrict__ xg,  // [B][T][G] bf16
                                             const unsigned char* __restrict__ wT8,  // [G][H] fp8
                                             const float* __restrict__ bias,         // [G]
                                             const int* __restrict__ seq_len,        // [B]
                                             unsigned char* __restrict__ h8,         // [T+1][B][H] fp8
                                             unsigned short* __restrict__ hb,        // [B][H] bf16 (final)
                                             float* __restrict__ hs,                 // [B][T][H]
                                             float* __restrict__ cs,                 // [B][T][H]
                                             unsigned int* __restrict__ flags) {     // [NWG_]
    const int wg = blockIdx.x;
    const int rb = wg >> 6, cb = wg & 63;   // rb-group contiguous in wg (r7 fix)
    const int tid = threadIdx.x;
    const int w = tid >> 6, l = tid & 63, g = l >> 4, li = l & 15;

    __shared__ unsigned char Bs8[64 * 1024];  // 64 KB fp8 weights, fragment order

    // stage B once in fragment order: granule gidx = (q*32+kk)*64 + lane holds
    // wT8[(q*1024 + cb*16 + (lane&15))*H + kk*32 + (lane>>4)*8 .. +7]  (8B)
    for (int gi = 0; gi < 32; ++gi) {
        int gidx = gi * 256 + tid;            // 0..8191
        int ls = gidx & 63;
        int frag = gidx >> 6;                 // 0..127
        int kk = frag & 31, q = frag >> 5;
        int col = q * 1024 + cb * 16 + (ls & 15);
        const unsigned char* src = wT8 + (size_t)col * H_ + kk * 32 + (ls >> 4) * 8;
        *(long*)(Bs8 + (size_t)gidx * 8) = *(const long*)src;
    }

    const int hc = cb * 16 + li;
    float bv[4];
#pragma unroll
    for (int q = 0; q < 4; ++q) bv[q] = bias[q * 1024 + hc];
    const int m0 = rb * 64 + w * 16 + g * 4;
    int sl[4];
#pragma unroll
    for (int r = 0; r < 4; ++r) sl[r] = seq_len[m0 + r];
    float creg[4] = {0.f, 0.f, 0.f, 0.f};
    float hreg[4] = {0.f, 0.f, 0.f, 0.f};

    const int arow_i = rb * 64 + w * 16 + li;
    const unsigned char* bbase = Bs8 + l * 8;   // fragment order: lane-linear
    // wave-0 poll target: lane tid covers flag rb*64 + tid
    const unsigned int* fp = flags + (rb << 6) + tid;

    __syncthreads();  // Bs8 ready (block-local)

// plain cached 8B loads (L2-broadcast path; addresses unique per step)
#define LOADS(buf, c) do { _Pragma("unroll") \
    for (int p = 0; p < 8; ++p) buf[p] = *(const long*)(arow8 + ((c) + p) * 32); } while (0)

// fragment-order B read: uniform offset (q*32+kk)*512, lane-linear base
#define MFMAS(buf, c) do { _Pragma("unroll") \
    for (int p = 0; p < 8; ++p) { \
        const int kk = (c) + p; \
        _Pragma("unroll") \
        for (int q = 0; q < 4; ++q) { \
            long bfv = *(const long*)(bbase + (((q * 32 + kk)) << 9)); \
            acc[q] = __builtin_amdgcn_mfma_f32_16x16x32_fp8_fp8(buf[p], bfv, acc[q], 0, 0, 0); \
        } } } while (0)

    // prologue: prefetch xg for t=0
    unsigned short xgr[4][4];
#pragma unroll
    for (int r = 0; r < 4; ++r) {
        const size_t xoff = ((size_t)(m0 + r) * T_ + 0) * G_ + hc;
#pragma unroll
        for (int q = 0; q < 4; ++q) xgr[r][q] = xg[xoff + q * 1024];
    }
    asm volatile("" ::: "memory");

    for (int t = 0; t < T_; ++t) {
        const unsigned char* h_in = h8 + (size_t)t * (B_ * H_);
        unsigned char* h_out = (unsigned char*)h8 + (size_t)(t + 1) * (B_ * H_);
        const unsigned char* arow8 = h_in + (size_t)arow_i * H_ + g * 8;

        // A-fragment pipeline: plain cached loads, 8-deep double buffer (r13 schedule)
        f32x4 acc[4] = {};
        long A0[8], A1[8];
        LOADS(A0, 0);
        DRAIN();
        LOADS(A1, 8);
        MFMAS(A0, 0);
        DRAIN();
        LOADS(A0, 16);
        MFMAS(A1, 8);
        DRAIN();
        LOADS(A1, 24);
        MFMAS(A0, 16);
        DRAIN();
        MFMAS(A1, 24);

        // pointwise + masked update; lane owns rows m0..m0+3 x col hc
        float hsv[4], csv[4];
#pragma unroll
        for (int r = 0; r < 4; ++r) {
            const int m = m0 + r;
            float ig = sigmoid_f(acc[0][r] + bv[0] + bf2f(xgr[r][0]));
            float fg = sigmoid_f(acc[1][r] + bv[1] + bf2f(xgr[r][1]));
            float gg = tanh_f(acc[2][r] + bv[2] + bf2f(xgr[r][2]));
            float og = sigmoid_f(acc[3][r] + bv[3] + bf2f(xgr[r][3]));
            float cn = fg * creg[r] + ig * gg;
            float hn = og * tanh_f(cn);
            bool valid = t < sl[r];
            if (valid) { creg[r] = cn; hreg[r] = hn; }
            hsv[r] = valid ? hn : 0.0f;
            csv[r] = valid ? cn : 0.0f;
            STBYTEC(h_out + (size_t)m * H_ + hc, f2fp8(hreg[r]));
        }

        // publish h_out (only the 4 write-through fp8 stores pending)
        DRAIN();
        __syncthreads();      // whole WG published
        const unsigned int tp1 = (unsigned int)(t + 1);
        if (tid == 0) {
            STDWC(flags + wg, tp1);
        }

        // off-critical-path: hs/cs outputs for this step
#pragma unroll
        for (int r = 0; r < 4; ++r) {
            const size_t ooff = ((size_t)(m0 + r) * T_ + t) * H_ + hc;
            __builtin_nontemporal_store(hsv[r], &hs[ooff]);
            __builtin_nontemporal_store(csv[r], &cs[ooff]);
        }

        if (t < T_ - 1) {
            // prefetch next step's xg under the barrier wait
#pragma unroll
            for (int r = 0; r < 4; ++r) {
                const size_t xoff = ((size_t)(m0 + r) * T_ + (t + 1)) * G_ + hc;
#pragma unroll
                for (int q = 0; q < 4; ++q) xgr[r][q] = xg[xoff + q * 1024];
            }
            asm volatile("" ::: "memory");
            if (tid < 64) {   // lane i waits for producer WG rb*64+i
                while (ld_u32_cohere(fp) < tp1) __builtin_amdgcn_s_sleep(1);
            }
            __syncthreads();
        }
    }
#undef LOADS
#undef MFMAS

    // final bf16 h for k_final (exact fp32 state, written once)
#pragma unroll
    for (int r = 0; r < 4; ++r)
        hb[(size_t)(m0 + r) * H_ + hc] = f2bf(hreg[r]);
}

// ---------------------------------------------------------------------------
// final_hidden[B][H] = tanh(h_last @ aff_w + aff_b)   (unchanged)
__global__ __launch_bounds__(256) void k_final(const unsigned short* __restrict__ h,
                                               const unsigned short* __restrict__ wT,
                                               const float* __restrict__ bias,
                                               float* __restrict__ fin) {
    const int rb = blockIdx.x & 3;
    const int nb = blockIdx.x >> 2;
    const int tid = threadIdx.x;
    const int w = tid >> 6;
    const int l = tid & 63;
    const int g = l >> 4, li = l & 15;

    __shared__ unsigned short As[64][40];
    __shared__ unsigned short Bs[64][40];

    const int srow = tid >> 2;
    const int scol = (tid & 3) * 8;
    const unsigned short* aptr = h + (size_t)(rb * 64 + srow) * H_ + scol;
    const unsigned short* bptr = wT + (size_t)(nb * 64 + srow) * H_ + scol;

    f32x4 acc[4] = {};
    int4 ra = *(const int4*)aptr;
    int4 rb2 = *(const int4*)bptr;
    for (int kk = 0; kk < H_; kk += 32) {
        *(int4*)&As[srow][scol] = ra;
        *(int4*)&Bs[srow][scol] = rb2;
        __syncthreads();
        if (kk + 32 < H_) {
            ra = *(const int4*)(aptr + kk + 32);
            rb2 = *(const int4*)(bptr + kk + 32);
        }
        short8 af = *(const short8*)&As[w * 16 + li][g * 8];
#pragma unroll
        for (int q = 0; q < 4; ++q) {
            short8 bf = *(const short8*)&Bs[q * 16 + li][g * 8];
            acc[q] = __builtin_amdgcn_mfma_f32_16x16x32_bf16(af, bf, acc[q], 0, 0, 0);
        }
        __syncthreads();
    }
    const int m0 = rb * 64 + w * 16 + g * 4;
#pragma unroll
    for (int q = 0; q < 4; ++q) {
        int col = nb * 64 + q * 16 + li;
        float bv = bias[col];
#pragma unroll
        for (int r = 0; r < 4; ++r)
            fin[(size_t)(m0 + r) * H_ + col] = tanh_f(acc[q][r] + bv);
    }
}

// ---------------------------------------------------------------------------
__global__ __launch_bounds__(256) void k_mask(const int* __restrict__ seq_len,
                                              float* __restrict__ mask) {
    int i = blockIdx.x * 256 + threadIdx.x;
    int b = i >> 6, t = i & 63;
    mask[i] = (t < seq_len[b]) ? 1.0f : 0.0f;
}

// ---------------------------------------------------------------------------
extern "C" void kernel_launch(void* const* d_in, const int* in_sizes, int n_in,
                              void* d_out, int out_size, void* d_ws, size_t ws_size,
                              hipStream_t stream) {
    const int* seq = (const int*)d_in[0];
    const int* seq_len = (const int*)d_in[1];
    const float* embed = (const float*)d_in[2];
    const float* x2h_w = (const float*)d_in[3];
    const float* x2h_b = (const float*)d_in[4];
    const float* h2h_w = (const float*)d_in[5];
    const float* h2h_b = (const float*)d_in[6];
    const float* aff_w = (const float*)d_in[7];
    const float* aff_b = (const float*)d_in[8];

    float* out = (float*)d_out;
    float* hs = out;
    float* cs = out + (size_t)B_ * T_ * H_;
    float* fin = cs + (size_t)B_ * T_ * H_;
    float* mask = fin + (size_t)B_ * H_;

    char* p = (char*)d_ws;
    unsigned short* emb_b = (unsigned short*)p; p += (size_t)V_ * E_ * 2;
    unsigned short* x2h_t = (unsigned short*)p; p += (size_t)G_ * E_ * 2;
    unsigned char*  h2h_8 = (unsigned char*)p;  p += (size_t)G_ * H_;
    unsigned short* aff_t = (unsigned short*)p; p += (size_t)H_ * H_ * 2;
    unsigned short* xg    = (unsigned short*)p; p += (size_t)B_ * T_ * G_ * 2;
    unsigned char*  h8    = (unsigned char*)p;  p += (size_t)(T_ + 1) * B_ * H_;  // 16.6 MB
    unsigned short* hbuf  = (unsigned short*)p; p += (size_t)B_ * H_ * 2;
    unsigned int*   flags = (unsigned int*)p;   p += NWG_ * sizeof(unsigned int);

    // 1) precompute bf16 operands (+ fp8 h2h weights, direct transpose)
    hipLaunchKernelGGL(k_cvt, dim3((V_ * E_ / 4 + 255) / 256), dim3(256), 0, stream,
                       embed, emb_b, V_ * E_ / 4);
    hipLaunchKernelGGL(k_transpose, dim3((E_ / 32) * (G_ / 32)), dim3(256), 0, stream,
                       x2h_w, x2h_t, E_, G_);
    hipLaunchKernelGGL(k_transpose8, dim3((H_ / 32) * (G_ / 32)), dim3(256), 0, stream,
                       h2h_w, h2h_8, H_, G_);
    hipLaunchKernelGGL(k_transpose, dim3((H_ / 32) * (H_ / 32)), dim3(256), 0, stream,
                       aff_w, aff_t, H_, H_);

    // 2) xg = embed[seq] @ x2h_w + b
    hipLaunchKernelGGL(k_xg, dim3(128 * 32), dim3(256), 0, stream,
                       seq, emb_b, x2h_t, x2h_b, xg);

    // 3) zero h8[0] (t=0 input) + flags (every launch)
    hipMemsetAsync(h8, 0, (size_t)B_ * H_, stream);
    hipMemsetAsync(flags, 0, NWG_ * sizeof(unsigned int), stream);

    // 4) persistent cooperative recurrence (fp8 matmul, per-step h buffers)
    {
        const unsigned short* xg_p = xg;
        const unsigned char* wT8_p = h2h_8;
        const float* b_p = h2h_b;
        const int* sl_p = seq_len;
        unsigned char* h8_p = h8;
        unsigned short* hb_p = hbuf;
        float* hs_p = hs;
        float* cs_p = cs;
        unsigned int* fl_p = flags;
        void* args[] = {(void*)&xg_p, (void*)&wT8_p, (void*)&b_p, (void*)&sl_p,
                        (void*)&h8_p, (void*)&hb_p,
                        (void*)&hs_p, (void*)&cs_p, (void*)&fl_p};
        hipLaunchCooperativeKernel(reinterpret_cast<void*>(k_rnn), dim3(NWG_), dim3(256),
                                   args, 0, stream);
    }

    // 5) final affine (bf16 h written once by k_rnn epilogue) + mask
    hipLaunchKernelGGL(k_final, dim3(64), dim3(256), 0, stream, hbuf, aff_t, aff_b, fin);
    hipLaunchKernelGGL(k_mask, dim3(B_ * T_ / 256), dim3(256), 0, stream, seq_len, mask);
}

// Round 17
// 578.647 us; speedup vs baseline: 1.1933x; 1.0267x over previous
//
#include <hip/hip_runtime.h>

// Problem constants
#define B_ 256
#define T_ 64
#define V_ 10000
#define E_ 512
#define H_ 1024
#define G_ 4096   // 4*H
#define NWG_ 256

typedef __attribute__((ext_vector_type(8))) short short8;
typedef __attribute__((ext_vector_type(4))) float f32x4;

static __device__ __forceinline__ float bf2f(unsigned short u) {
    return __uint_as_float(((unsigned int)u) << 16);
}
static __device__ __forceinline__ unsigned short f2bf(float f) {
    unsigned int i = __float_as_uint(f);
    unsigned int r = (i + 0x7FFFu + ((i >> 16) & 1u)) >> 16;
    return (unsigned short)r;
}
static __device__ __forceinline__ float sigmoid_f(float x) {
    return 1.0f / (1.0f + __expf(-x));
}
static __device__ __forceinline__ float tanh_f(float x) {
    return 1.0f - 2.0f / (__expf(2.0f * x) + 1.0f);
}
// fp8 e4m3 (OCP) conversion via gfx950 packed-convert
static __device__ __forceinline__ unsigned int f2fp8(float f) {
    int pk = __builtin_amdgcn_cvt_pk_fp8_f32(f, f, 0, false);
    return (unsigned int)(pk & 0xFF);
}

// async global->LDS, 16B per lane
static __device__ __forceinline__ void gload16(const void* g, void* l) {
    __builtin_amdgcn_global_load_lds((const __attribute__((address_space(1))) void*)g,
                                     (__attribute__((address_space(3))) void*)l, 16, 0, 0);
}

// --- agent-coherent primitives (proven rounds 4/7/8/13) ---------------------
// drain all vmem, then block scheduler motion across (rule #18)
#define DRAIN() do { asm volatile("s_waitcnt vmcnt(0)" ::: "memory"); \
                     __builtin_amdgcn_sched_barrier(0); } while (0)
// 1B coherent store (write-through to fabric/L3)
#define STBYTEC(ptr, val) \
    asm volatile("global_store_byte %0, %1, off sc0 sc1" :: "v"(ptr), "v"(val) : "memory")
// 4B coherent store
#define STDWC(ptr, val) \
    asm volatile("global_store_dword %0, %1, off sc0 sc1" :: "v"(ptr), "v"(val) : "memory")

static __device__ __forceinline__ unsigned ld_u32_cohere(const void* p) {
    unsigned r;
    asm volatile("global_load_dword %0, %1, off sc0 sc1\n\ts_waitcnt vmcnt(0)"
                 : "=v"(r) : "v"(p) : "memory");
    return r;
}

// ---------------------------------------------------------------------------
// fp32 -> bf16 convert
__global__ __launch_bounds__(256) void k_cvt(const float* __restrict__ in,
                                             unsigned short* __restrict__ out, int n4) {
    int i = blockIdx.x * 256 + threadIdx.x;
    if (i >= n4) return;
    float4 v = reinterpret_cast<const float4*>(in)[i];
    uint2 p;
    p.x = (unsigned int)f2bf(v.x) | ((unsigned int)f2bf(v.y) << 16);
    p.y = (unsigned int)f2bf(v.z) | ((unsigned int)f2bf(v.w) << 16);
    reinterpret_cast<uint2*>(out)[i] = p;
}

// ---------------------------------------------------------------------------
// W[K][N] fp32 -> WT[N][K] bf16
__global__ __launch_bounds__(256) void k_transpose(const float* __restrict__ w,
                                                   unsigned short* __restrict__ wT,
                                                   int K, int N) {
    __shared__ float tile[32][33];
    int nblk = N >> 5;
    int bx = blockIdx.x % nblk;
    int by = blockIdx.x / nblk;
    int lx = threadIdx.x & 31;
    int ly = threadIdx.x >> 5;
    int k0 = by * 32, n0 = bx * 32;
#pragma unroll
    for (int i = 0; i < 32; i += 8)
        tile[ly + i][lx] = w[(size_t)(k0 + ly + i) * N + n0 + lx];
    __syncthreads();
#pragma unroll
    for (int i = 0; i < 32; i += 8)
        wT[(size_t)(n0 + ly + i) * K + k0 + lx] = f2bf(tile[lx][ly + i]);
}

// ---------------------------------------------------------------------------
// W[K][N] fp32 -> WT[N][K] fp8 e4m3 (direct)
__global__ __launch_bounds__(256) void k_transpose8(const float* __restrict__ w,
                                                    unsigned char* __restrict__ wT,
                                                    int K, int N) {
    __shared__ float tile[32][33];
    int nblk = N >> 5;
    int bx = blockIdx.x % nblk;
    int by = blockIdx.x / nblk;
    int lx = threadIdx.x & 31;
    int ly = threadIdx.x >> 5;
    int k0 = by * 32, n0 = bx * 32;
#pragma unroll
    for (int i = 0; i < 32; i += 8)
        tile[ly + i][lx] = w[(size_t)(k0 + ly + i) * N + n0 + lx];
    __syncthreads();
#pragma unroll
    for (int i = 0; i < 32; i += 8)
        wT[(size_t)(n0 + ly + i) * K + k0 + lx] = (unsigned char)f2fp8(tile[lx][ly + i]);
}

// ---------------------------------------------------------------------------
// xg[B*T][G] = bf16( embed[seq] @ x2h_w + x2h_b )   (r16 version, unchanged)
__global__ __launch_bounds__(256) void k_xg(const int* __restrict__ seq,
                                            const unsigned short* __restrict__ emb,  // [V][E]
                                            const unsigned short* __restrict__ wT,   // [G][E]
                                            const float* __restrict__ bias,          // [G]
                                            unsigned short* __restrict__ xg) {       // [B*T][G]
    const int mt = blockIdx.x & 127;
    const int nt = blockIdx.x >> 7;
    const int tid = threadIdx.x;
    const int w = tid >> 6, l = tid & 63, g = l >> 4, li = l & 15;
    const int wr = w >> 1, wc = w & 1;

    __shared__ unsigned short As[128 * 64];  // 16 KB
    __shared__ unsigned short Bs[128 * 64];  // 16 KB
    __shared__ int seqv[128];

    if (tid < 128) seqv[tid] = seq[mt * 128 + tid];
    __syncthreads();

    const int lr = l >> 3;                 // row-within-octet = row&7
    const int db = (l & 7) * 16;           // dest byte within 128B row
    const int sbel = (db ^ (lr << 4)) >> 1;  // pre-swizzled source element offset
    const unsigned short* asrc[4];
    const unsigned short* bsrc[4];
    char* adst[4];
    char* bdst[4];
#pragma unroll
    for (int j = 0; j < 4; ++j) {
        const int r = (j * 4 + w) * 8 + lr;
        asrc[j] = emb + (size_t)seqv[r] * E_ + sbel;
        bsrc[j] = wT + (size_t)(nt * 128 + r) * E_ + sbel;
        adst[j] = (char*)As + (j * 4 + w) * 1024;
        bdst[j] = (char*)Bs + (j * 4 + w) * 1024;
    }

    const char* Ab = (const char*)As;
    const char* Bb = (const char*)Bs;
    const int lx = (li & 7) << 4;          // read-side XOR (row&7 == li&7)

    f32x4 acc[4][4] = {};
    for (int k0 = 0; k0 < E_; k0 += 64) {
#pragma unroll
        for (int j = 0; j < 4; ++j) {
            gload16(asrc[j] + k0, adst[j]);
            gload16(bsrc[j] + k0, bdst[j]);
        }
        __syncthreads();
#pragma unroll
        for (int kc2 = 0; kc2 < 2; ++kc2) {
            const int kb = (kc2 * 64 + g * 16) ^ lx;
            short8 af[4], bf[4];
#pragma unroll
            for (int i = 0; i < 4; ++i) {
                af[i] = *(const short8*)(Ab + (wr * 64 + i * 16 + li) * 128 + kb);
                bf[i] = *(const short8*)(Bb + (wc * 64 + i * 16 + li) * 128 + kb);
            }
#pragma unroll
            for (int i = 0; i < 4; ++i)
#pragma unroll
                for (int j = 0; j < 4; ++j)
                    acc[i][j] = __builtin_amdgcn_mfma_f32_16x16x32_bf16(af[i], bf[j], acc[i][j], 0, 0, 0);
        }
        __syncthreads();
    }

#pragma unroll
    for (int j = 0; j < 4; ++j) {
        const int col = nt * 128 + wc * 64 + j * 16 + li;
        const float bv = bias[col];
#pragma unroll
        for (int i = 0; i < 4; ++i) {
            const int row = mt * 128 + wr * 64 + i * 16 + g * 4;
#pragma unroll
            for (int r = 0; r < 4; ++r)
                xg[(size_t)(row + r) * G_ + col] = f2bf(acc[i][j][r] + bv);
        }
    }
}

// ---------------------------------------------------------------------------
// Persistent LSTM recurrence, cooperative launch (256 WGs = 1/CU).
// r17 change vs r16 (one mapping edit): rb = wg&3 (XCD-aligned — with
// wg->XCD ~ wg%8, all 32 WGs on an XCD share wg&3, hence ONE 64KB h-slice
// per XCD per step instead of all four). Safe without invalidation because
// h flows through per-step buffers (r15): consumer lines are always cold.
// Poll window matches the STRIDED producer set: lane i polls flags[rb+4*i]
// (poll set == producer set — the r5-bug invariant, done right).
__global__ __launch_bounds__(256) void k_rnn(const unsigned short* __restrict__ xg,  // [B][T][G] bf16
                                             const unsigned char* __restrict__ wT8,  // [G][H] fp8
                                             const float* __restrict__ bias,         // [G]
                                             const int* __restrict__ seq_len,        // [B]
                                             unsigned char* __restrict__ h8,         // [T+1][B][H] fp8
                                             unsigned short* __restrict__ hb,        // [B][H] bf16 (final)
                                             float* __restrict__ hs,                 // [B][T][H]
                                             float* __restrict__ cs,                 // [B][T][H]
                                             unsigned int* __restrict__ flags) {     // [NWG_]
    const int wg = blockIdx.x;
    const int rb = wg & 3, cb = wg >> 2;   // XCD-aligned row group
    const int tid = threadIdx.x;
    const int w = tid >> 6, l = tid & 63, g = l >> 4, li = l & 15;

    __shared__ unsigned char Bs8[64 * 1024];  // 64 KB fp8 weights, fragment order

    // stage B once in fragment order: granule gidx = (q*32+kk)*64 + lane holds
    // wT8[(q*1024 + cb*16 + (lane&15))*H + kk*32 + (lane>>4)*8 .. +7]  (8B)
    for (int gi = 0; gi < 32; ++gi) {
        int gidx = gi * 256 + tid;            // 0..8191
        int ls = gidx & 63;
        int frag = gidx >> 6;                 // 0..127
        int kk = frag & 31, q = frag >> 5;
        int col = q * 1024 + cb * 16 + (ls & 15);
        const unsigned char* src = wT8 + (size_t)col * H_ + kk * 32 + (ls >> 4) * 8;
        *(long*)(Bs8 + (size_t)gidx * 8) = *(const long*)src;
    }

    const int hc = cb * 16 + li;
    float bv[4];
#pragma unroll
    for (int q = 0; q < 4; ++q) bv[q] = bias[q * 1024 + hc];
    const int m0 = rb * 64 + w * 16 + g * 4;
    int sl[4];
#pragma unroll
    for (int r = 0; r < 4; ++r) sl[r] = seq_len[m0 + r];
    float creg[4] = {0.f, 0.f, 0.f, 0.f};
    float hreg[4] = {0.f, 0.f, 0.f, 0.f};

    const int arow_i = rb * 64 + w * 16 + li;
    const unsigned char* bbase = Bs8 + l * 8;   // fragment order: lane-linear
    // strided poll: lane tid (<64) covers producer WG rb + 4*tid
    const unsigned int* fp = flags + rb + 4 * tid;

    __syncthreads();  // Bs8 ready (block-local)

// plain cached 8B loads (L2-broadcast path; addresses unique per step)
#define LOADS(buf, c) do { _Pragma("unroll") \
    for (int p = 0; p < 8; ++p) buf[p] = *(const long*)(arow8 + ((c) + p) * 32); } while (0)

// fragment-order B read: uniform offset (q*32+kk)*512, lane-linear base
#define MFMAS(buf, c) do { _Pragma("unroll") \
    for (int p = 0; p < 8; ++p) { \
        const int kk = (c) + p; \
        _Pragma("unroll") \
        for (int q = 0; q < 4; ++q) { \
            long bfv = *(const long*)(bbase + (((q * 32 + kk)) << 9)); \
            acc[q] = __builtin_amdgcn_mfma_f32_16x16x32_fp8_fp8(buf[p], bfv, acc[q], 0, 0, 0); \
        } } } while (0)

    // prologue: prefetch xg for t=0
    unsigned short xgr[4][4];
#pragma unroll
    for (int r = 0; r < 4; ++r) {
        const size_t xoff = ((size_t)(m0 + r) * T_ + 0) * G_ + hc;
#pragma unroll
        for (int q = 0; q < 4; ++q) xgr[r][q] = xg[xoff + q * 1024];
    }
    asm volatile("" ::: "memory");

    for (int t = 0; t < T_; ++t) {
        const unsigned char* h_in = h8 + (size_t)t * (B_ * H_);
        unsigned char* h_out = (unsigned char*)h8 + (size_t)(t + 1) * (B_ * H_);
        const unsigned char* arow8 = h_in + (size_t)arow_i * H_ + g * 8;

        // A-fragment pipeline: plain cached loads, 8-deep double buffer (r13 schedule)
        f32x4 acc[4] = {};
        long A0[8], A1[8];
        LOADS(A0, 0);
        DRAIN();
        LOADS(A1, 8);
        MFMAS(A0, 0);
        DRAIN();
        LOADS(A0, 16);
        MFMAS(A1, 8);
        DRAIN();
        LOADS(A1, 24);
        MFMAS(A0, 16);
        DRAIN();
        MFMAS(A1, 24);

        // pointwise + masked update; lane owns rows m0..m0+3 x col hc
        float hsv[4], csv[4];
#pragma unroll
        for (int r = 0; r < 4; ++r) {
            const int m = m0 + r;
            float ig = sigmoid_f(acc[0][r] + bv[0] + bf2f(xgr[r][0]));
            float fg = sigmoid_f(acc[1][r] + bv[1] + bf2f(xgr[r][1]));
            float gg = tanh_f(acc[2][r] + bv[2] + bf2f(xgr[r][2]));
            float og = sigmoid_f(acc[3][r] + bv[3] + bf2f(xgr[r][3]));
            float cn = fg * creg[r] + ig * gg;
            float hn = og * tanh_f(cn);
            bool valid = t < sl[r];
            if (valid) { creg[r] = cn; hreg[r] = hn; }
            hsv[r] = valid ? hn : 0.0f;
            csv[r] = valid ? cn : 0.0f;
            STBYTEC(h_out + (size_t)m * H_ + hc, f2fp8(hreg[r]));
        }

        // publish h_out (only the 4 write-through fp8 stores pending)
        DRAIN();
        __syncthreads();      // whole WG published
        const unsigned int tp1 = (unsigned int)(t + 1);
        if (tid == 0) {
            STDWC(flags + wg, tp1);
        }

        // off-critical-path: hs/cs outputs for this step
#pragma unroll
        for (int r = 0; r < 4; ++r) {
            const size_t ooff = ((size_t)(m0 + r) * T_ + t) * H_ + hc;
            __builtin_nontemporal_store(hsv[r], &hs[ooff]);
            __builtin_nontemporal_store(csv[r], &cs[ooff]);
        }

        if (t < T_ - 1) {
            // prefetch next step's xg under the barrier wait
#pragma unroll
            for (int r = 0; r < 4; ++r) {
                const size_t xoff = ((size_t)(m0 + r) * T_ + (t + 1)) * G_ + hc;
#pragma unroll
                for (int q = 0; q < 4; ++q) xgr[r][q] = xg[xoff + q * 1024];
            }
            asm volatile("" ::: "memory");
            if (tid < 64) {   // lane i waits for producer WG rb + 4*i
                while (ld_u32_cohere(fp) < tp1) __builtin_amdgcn_s_sleep(1);
            }
            __syncthreads();
        }
    }
#undef LOADS
#undef MFMAS

    // final bf16 h for k_final (exact fp32 state, written once)
#pragma unroll
    for (int r = 0; r < 4; ++r)
        hb[(size_t)(m0 + r) * H_ + hc] = f2bf(hreg[r]);
}

// ---------------------------------------------------------------------------
// final_hidden[B][H] = tanh(h_last @ aff_w + aff_b)   (unchanged)
__global__ __launch_bounds__(256) void k_final(const unsigned short* __restrict__ h,
                                               const unsigned short* __restrict__ wT,
                                               const float* __restrict__ bias,
                                               float* __restrict__ fin) {
    const int rb = blockIdx.x & 3;
    const int nb = blockIdx.x >> 2;
    const int tid = threadIdx.x;
    const int w = tid >> 6;
    const int l = tid & 63;
    const int g = l >> 4, li = l & 15;

    __shared__ unsigned short As[64][40];
    __shared__ unsigned short Bs[64][40];

    const int srow = tid >> 2;
    const int scol = (tid & 3) * 8;
    const unsigned short* aptr = h + (size_t)(rb * 64 + srow) * H_ + scol;
    const unsigned short* bptr = wT + (size_t)(nb * 64 + srow) * H_ + scol;

    f32x4 acc[4] = {};
    int4 ra = *(const int4*)aptr;
    int4 rb2 = *(const int4*)bptr;
    for (int kk = 0; kk < H_; kk += 32) {
        *(int4*)&As[srow][scol] = ra;
        *(int4*)&Bs[srow][scol] = rb2;
        __syncthreads();
        if (kk + 32 < H_) {
            ra = *(const int4*)(aptr + kk + 32);
            rb2 = *(const int4*)(bptr + kk + 32);
        }
        short8 af = *(const short8*)&As[w * 16 + li][g * 8];
#pragma unroll
        for (int q = 0; q < 4; ++q) {
            short8 bf = *(const short8*)&Bs[q * 16 + li][g * 8];
            acc[q] = __builtin_amdgcn_mfma_f32_16x16x32_bf16(af, bf, acc[q], 0, 0, 0);
        }
        __syncthreads();
    }
    const int m0 = rb * 64 + w * 16 + g * 4;
#pragma unroll
    for (int q = 0; q < 4; ++q) {
        int col = nb * 64 + q * 16 + li;
        float bv = bias[col];
#pragma unroll
        for (int r = 0; r < 4; ++r)
            fin[(size_t)(m0 + r) * H_ + col] = tanh_f(acc[q][r] + bv);
    }
}

// ---------------------------------------------------------------------------
__global__ __launch_bounds__(256) void k_mask(const int* __restrict__ seq_len,
                                              float* __restrict__ mask) {
    int i = blockIdx.x * 256 + threadIdx.x;
    int b = i >> 6, t = i & 63;
    mask[i] = (t < seq_len[b]) ? 1.0f : 0.0f;
}

// ---------------------------------------------------------------------------
extern "C" void kernel_launch(void* const* d_in, const int* in_sizes, int n_in,
                              void* d_out, int out_size, void* d_ws, size_t ws_size,
                              hipStream_t stream) {
    const int* seq = (const int*)d_in[0];
    const int* seq_len = (const int*)d_in[1];
    const float* embed = (const float*)d_in[2];
    const float* x2h_w = (const float*)d_in[3];
    const float* x2h_b = (const float*)d_in[4];
    const float* h2h_w = (const float*)d_in[5];
    const float* h2h_b = (const float*)d_in[6];
    const float* aff_w = (const float*)d_in[7];
    const float* aff_b = (const float*)d_in[8];

    float* out = (float*)d_out;
    float* hs = out;
    float* cs = out + (size_t)B_ * T_ * H_;
    float* fin = cs + (size_t)B_ * T_ * H_;
    float* mask = fin + (size_t)B_ * H_;

    char* p = (char*)d_ws;
    unsigned short* emb_b = (unsigned short*)p; p += (size_t)V_ * E_ * 2;
    unsigned short* x2h_t = (unsigned short*)p; p += (size_t)G_ * E_ * 2;
    unsigned char*  h2h_8 = (unsigned char*)p;  p += (size_t)G_ * H_;
    unsigned short* aff_t = (unsigned short*)p; p += (size_t)H_ * H_ * 2;
    unsigned short* xg    = (unsigned short*)p; p += (size_t)B_ * T_ * G_ * 2;
    unsigned char*  h8    = (unsigned char*)p;  p += (size_t)(T_ + 1) * B_ * H_;  // 16.6 MB
    unsigned short* hbuf  = (unsigned short*)p; p += (size_t)B_ * H_ * 2;
    unsigned int*   flags = (unsigned int*)p;   p += NWG_ * sizeof(unsigned int);

    // 1) precompute bf16 operands (+ fp8 h2h weights, direct transpose)
    hipLaunchKernelGGL(k_cvt, dim3((V_ * E_ / 4 + 255) / 256), dim3(256), 0, stream,
                       embed, emb_b, V_ * E_ / 4);
    hipLaunchKernelGGL(k_transpose, dim3((E_ / 32) * (G_ / 32)), dim3(256), 0, stream,
                       x2h_w, x2h_t, E_, G_);
    hipLaunchKernelGGL(k_transpose8, dim3((H_ / 32) * (G_ / 32)), dim3(256), 0, stream,
                       h2h_w, h2h_8, H_, G_);
    hipLaunchKernelGGL(k_transpose, dim3((H_ / 32) * (H_ / 32)), dim3(256), 0, stream,
                       aff_w, aff_t, H_, H_);

    // 2) xg = embed[seq] @ x2h_w + b
    hipLaunchKernelGGL(k_xg, dim3(128 * 32), dim3(256), 0, stream,
                       seq, emb_b, x2h_t, x2h_b, xg);

    // 3) zero h8[0] (t=0 input) + flags (every launch)
    hipMemsetAsync(h8, 0, (size_t)B_ * H_, stream);
    hipMemsetAsync(flags, 0, NWG_ * sizeof(unsigned int), stream);

    // 4) persistent cooperative recurrence (fp8 matmul, per-step h buffers)
    {
        const unsigned short* xg_p = xg;
        const unsigned char* wT8_p = h2h_8;
        const float* b_p = h2h_b;
        const int* sl_p = seq_len;
        unsigned char* h8_p = h8;
        unsigned short* hb_p = hbuf;
        float* hs_p = hs;
        float* cs_p = cs;
        unsigned int* fl_p = flags;
        void* args[] = {(void*)&xg_p, (void*)&wT8_p, (void*)&b_p, (void*)&sl_p,
                        (void*)&h8_p, (void*)&hb_p,
                        (void*)&hs_p, (void*)&cs_p, (void*)&fl_p};
        hipLaunchCooperativeKernel(reinterpret_cast<void*>(k_rnn), dim3(NWG_), dim3(256),
                                   args, 0, stream);
    }

    // 5) final affine (bf16 h written once by k_rnn epilogue) + mask
    hipLaunchKernelGGL(k_final, dim3(64), dim3(256), 0, stream, hbuf, aff_t, aff_b, fin);
    hipLaunchKernelGGL(k_mask, dim3(B_ * T_ / 256), dim3(256), 0, stream, seq_len, mask);
}

// Round 18
// 561.199 us; speedup vs baseline: 1.2304x; 1.0311x over previous
//
#include <hip/hip_runtime.h>

// Problem constants
#define B_ 256
#define T_ 64
#define V_ 10000
#define E_ 512
#define H_ 1024
#define G_ 4096   // 4*H
#define NWG_ 256

typedef __attribute__((ext_vector_type(8))) short short8;
typedef __attribute__((ext_vector_type(4))) float f32x4;

static __device__ __forceinline__ float bf2f(unsigned short u) {
    return __uint_as_float(((unsigned int)u) << 16);
}
static __device__ __forceinline__ unsigned short f2bf(float f) {
    unsigned int i = __float_as_uint(f);
    unsigned int r = (i + 0x7FFFu + ((i >> 16) & 1u)) >> 16;
    return (unsigned short)r;
}
static __device__ __forceinline__ float sigmoid_f(float x) {
    return 1.0f / (1.0f + __expf(-x));
}
static __device__ __forceinline__ float tanh_f(float x) {
    return 1.0f - 2.0f / (__expf(2.0f * x) + 1.0f);
}
// fp8 e4m3 (OCP) conversion via gfx950 packed-convert
static __device__ __forceinline__ unsigned int f2fp8(float f) {
    int pk = __builtin_amdgcn_cvt_pk_fp8_f32(f, f, 0, false);
    return (unsigned int)(pk & 0xFF);
}

// async global->LDS, 16B per lane
static __device__ __forceinline__ void gload16(const void* g, void* l) {
    __builtin_amdgcn_global_load_lds((const __attribute__((address_space(1))) void*)g,
                                     (__attribute__((address_space(3))) void*)l, 16, 0, 0);
}

// --- agent-coherent primitives (proven rounds 4/7/8/13) ---------------------
#define DRAIN() do { asm volatile("s_waitcnt vmcnt(0)" ::: "memory"); \
                     __builtin_amdgcn_sched_barrier(0); } while (0)
#define STBYTEC(ptr, val) \
    asm volatile("global_store_byte %0, %1, off sc0 sc1" :: "v"(ptr), "v"(val) : "memory")
#define STDWC(ptr, val) \
    asm volatile("global_store_dword %0, %1, off sc0 sc1" :: "v"(ptr), "v"(val) : "memory")

static __device__ __forceinline__ unsigned ld_u32_cohere(const void* p) {
    unsigned r;
    asm volatile("global_load_dword %0, %1, off sc0 sc1\n\ts_waitcnt vmcnt(0)"
                 : "=v"(r) : "v"(p) : "memory");
    return r;
}

// ---------------------------------------------------------------------------
// fp32 -> fp8 e4m3 convert (4 elems/thread)
__global__ __launch_bounds__(256) void k_cvt8f(const float* __restrict__ in,
                                               unsigned char* __restrict__ out, int n4) {
    int i = blockIdx.x * 256 + threadIdx.x;
    if (i >= n4) return;
    float4 v = reinterpret_cast<const float4*>(in)[i];
    int p0 = __builtin_amdgcn_cvt_pk_fp8_f32(v.x, v.y, 0, false);
    int p1 = __builtin_amdgcn_cvt_pk_fp8_f32(v.z, v.w, 0, false);
    unsigned int word = ((unsigned int)p0 & 0xFFFFu) | (((unsigned int)p1 & 0xFFFFu) << 16);
    reinterpret_cast<unsigned int*>(out)[i] = word;
}

// ---------------------------------------------------------------------------
// W[K][N] fp32 -> WT[N][K] bf16
__global__ __launch_bounds__(256) void k_transpose(const float* __restrict__ w,
                                                   unsigned short* __restrict__ wT,
                                                   int K, int N) {
    __shared__ float tile[32][33];
    int nblk = N >> 5;
    int bx = blockIdx.x % nblk;
    int by = blockIdx.x / nblk;
    int lx = threadIdx.x & 31;
    int ly = threadIdx.x >> 5;
    int k0 = by * 32, n0 = bx * 32;
#pragma unroll
    for (int i = 0; i < 32; i += 8)
        tile[ly + i][lx] = w[(size_t)(k0 + ly + i) * N + n0 + lx];
    __syncthreads();
#pragma unroll
    for (int i = 0; i < 32; i += 8)
        wT[(size_t)(n0 + ly + i) * K + k0 + lx] = f2bf(tile[lx][ly + i]);
}

// ---------------------------------------------------------------------------
// W[K][N] fp32 -> WT[N][K] fp8 e4m3 (direct)
__global__ __launch_bounds__(256) void k_transpose8(const float* __restrict__ w,
                                                    unsigned char* __restrict__ wT,
                                                    int K, int N) {
    __shared__ float tile[32][33];
    int nblk = N >> 5;
    int bx = blockIdx.x % nblk;
    int by = blockIdx.x / nblk;
    int lx = threadIdx.x & 31;
    int ly = threadIdx.x >> 5;
    int k0 = by * 32, n0 = bx * 32;
#pragma unroll
    for (int i = 0; i < 32; i += 8)
        tile[ly + i][lx] = w[(size_t)(k0 + ly + i) * N + n0 + lx];
    __syncthreads();
#pragma unroll
    for (int i = 0; i < 32; i += 8)
        wT[(size_t)(n0 + ly + i) * K + k0 + lx] = (unsigned char)f2fp8(tile[lx][ly + i]);
}

// ---------------------------------------------------------------------------
// xg[B*T][G] = bf16( fp8(embed[seq]) @ fp8(x2h_w) + x2h_b )
// r18: fp8 operands halve the L2/L3 staging traffic (1.07 GB -> 540 MB, the
// k_xg bottleneck). 128x128 tile, BK=64; LDS 8KB+8KB; staging 4 gload16/iter
// (2 per matrix); 16B-slot XOR swizzle (slot ^= row&3) applied identically
// on store (pre-swizzled source) and read -> MFMA input-map invariant holds.
__global__ __launch_bounds__(256) void k_xg(const int* __restrict__ seq,
                                            const unsigned char* __restrict__ emb,  // [V][E] fp8
                                            const unsigned char* __restrict__ wT,   // [G][E] fp8
                                            const float* __restrict__ bias,         // [G]
                                            unsigned short* __restrict__ xg) {      // [B*T][G]
    const int mt = blockIdx.x & 127;
    const int nt = blockIdx.x >> 7;
    const int tid = threadIdx.x;
    const int w = tid >> 6, l = tid & 63, g = l >> 4, li = l & 15;
    const int wr = w >> 1, wc = w & 1;

    __shared__ unsigned char As8[128 * 64];  // 8 KB
    __shared__ unsigned char Bs8[128 * 64];  // 8 KB
    __shared__ int seqv[128];

    if (tid < 128) seqv[tid] = seq[mt * 128 + tid];
    __syncthreads();

    // staging: issue j in {0,1}; granule = (j*4+w)*64 + l; row = (j*4+w)*16 + (l>>2);
    // c = l&3 (16B slot); source slot pre-swizzled: c ^ (row&3)
    const unsigned char* asrc[2];
    const unsigned char* bsrc[2];
    char* adst[2];
    char* bdst[2];
#pragma unroll
    for (int j = 0; j < 2; ++j) {
        const int row = (j * 4 + w) * 16 + (l >> 2);
        const int sb = ((l & 3) << 4) ^ ((row & 3) << 4);  // swizzled byte offset in 64B row
        asrc[j] = emb + (size_t)seqv[row] * E_ + sb;
        bsrc[j] = wT + (size_t)(nt * 128 + row) * E_ + sb;
        adst[j] = (char*)As8 + (j * 4 + w) * 1024;
        bdst[j] = (char*)Bs8 + (j * 4 + w) * 1024;
    }

    const char* Ab = (const char*)As8;
    const char* Bb = (const char*)Bs8;
    const int lx3 = li & 3;        // row&3 for fragment rows (row = ..16*i + li)
    const int go = (g & 1) * 8;    // within-slot byte offset

    f32x4 acc[4][4] = {};
    for (int k0 = 0; k0 < E_; k0 += 64) {
#pragma unroll
        for (int j = 0; j < 2; ++j) {
            gload16(asrc[j] + k0, adst[j]);
            gload16(bsrc[j] + k0, bdst[j]);
        }
        __syncthreads();  // drains vmcnt -> LDS ready
#pragma unroll
        for (int kc2 = 0; kc2 < 2; ++kc2) {
            const int slot = (kc2 * 2 + (g >> 1)) ^ lx3;  // swizzled 16B slot
            const int kb = slot * 16 + go;
            long af[4], bf[4];
#pragma unroll
            for (int i = 0; i < 4; ++i) {
                af[i] = *(const long*)(Ab + (wr * 64 + i * 16 + li) * 64 + kb);
                bf[i] = *(const long*)(Bb + (wc * 64 + i * 16 + li) * 64 + kb);
            }
#pragma unroll
            for (int i = 0; i < 4; ++i)
#pragma unroll
                for (int j = 0; j < 4; ++j)
                    acc[i][j] = __builtin_amdgcn_mfma_f32_16x16x32_fp8_fp8(af[i], bf[j], acc[i][j], 0, 0, 0);
        }
        __syncthreads();  // compute done before next stage overwrites
    }

#pragma unroll
    for (int j = 0; j < 4; ++j) {
        const int col = nt * 128 + wc * 64 + j * 16 + li;
        const float bv = bias[col];
#pragma unroll
        for (int i = 0; i < 4; ++i) {
            const int row = mt * 128 + wr * 64 + i * 16 + g * 4;
#pragma unroll
            for (int r = 0; r < 4; ++r)
                xg[(size_t)(row + r) * G_ + col] = f2bf(acc[i][j][r] + bv);
        }
    }
}

// ---------------------------------------------------------------------------
// Persistent LSTM recurrence, cooperative launch (256 WGs = 1/CU).
// IDENTICAL to round 17 (best passing: ~460us): fp8 matmul, per-step h
// buffers (plain cached consumer loads), XCD-aligned rb = wg&3 with the
// matching strided poll, write-through producers, flag barrier.
__global__ __launch_bounds__(256) void k_rnn(const unsigned short* __restrict__ xg,  // [B][T][G] bf16
                                             const unsigned char* __restrict__ wT8,  // [G][H] fp8
                                             const float* __restrict__ bias,         // [G]
                                             const int* __restrict__ seq_len,        // [B]
                                             unsigned char* __restrict__ h8,         // [T+1][B][H] fp8
                                             unsigned short* __restrict__ hb,        // [B][H] bf16 (final)
                                             float* __restrict__ hs,                 // [B][T][H]
                                             float* __restrict__ cs,                 // [B][T][H]
                                             unsigned int* __restrict__ flags) {     // [NWG_]
    const int wg = blockIdx.x;
    const int rb = wg & 3, cb = wg >> 2;   // XCD-aligned row group
    const int tid = threadIdx.x;
    const int w = tid >> 6, l = tid & 63, g = l >> 4, li = l & 15;

    __shared__ unsigned char Bs8[64 * 1024];  // 64 KB fp8 weights, fragment order

    // stage B once in fragment order: granule gidx = (q*32+kk)*64 + lane holds
    // wT8[(q*1024 + cb*16 + (lane&15))*H + kk*32 + (lane>>4)*8 .. +7]  (8B)
    for (int gi = 0; gi < 32; ++gi) {
        int gidx = gi * 256 + tid;            // 0..8191
        int ls = gidx & 63;
        int frag = gidx >> 6;                 // 0..127
        int kk = frag & 31, q = frag >> 5;
        int col = q * 1024 + cb * 16 + (ls & 15);
        const unsigned char* src = wT8 + (size_t)col * H_ + kk * 32 + (ls >> 4) * 8;
        *(long*)(Bs8 + (size_t)gidx * 8) = *(const long*)src;
    }

    const int hc = cb * 16 + li;
    float bv[4];
#pragma unroll
    for (int q = 0; q < 4; ++q) bv[q] = bias[q * 1024 + hc];
    const int m0 = rb * 64 + w * 16 + g * 4;
    int sl[4];
#pragma unroll
    for (int r = 0; r < 4; ++r) sl[r] = seq_len[m0 + r];
    float creg[4] = {0.f, 0.f, 0.f, 0.f};
    float hreg[4] = {0.f, 0.f, 0.f, 0.f};

    const int arow_i = rb * 64 + w * 16 + li;
    const unsigned char* bbase = Bs8 + l * 8;   // fragment order: lane-linear
    // strided poll: lane tid (<64) covers producer WG rb + 4*tid
    const unsigned int* fp = flags + rb + 4 * tid;

    __syncthreads();  // Bs8 ready (block-local)

// plain cached 8B loads (L2-broadcast path; addresses unique per step)
#define LOADS(buf, c) do { _Pragma("unroll") \
    for (int p = 0; p < 8; ++p) buf[p] = *(const long*)(arow8 + ((c) + p) * 32); } while (0)

// fragment-order B read: uniform offset (q*32+kk)*512, lane-linear base
#define MFMAS(buf, c) do { _Pragma("unroll") \
    for (int p = 0; p < 8; ++p) { \
        const int kk = (c) + p; \
        _Pragma("unroll") \
        for (int q = 0; q < 4; ++q) { \
            long bfv = *(const long*)(bbase + (((q * 32 + kk)) << 9)); \
            acc[q] = __builtin_amdgcn_mfma_f32_16x16x32_fp8_fp8(buf[p], bfv, acc[q], 0, 0, 0); \
        } } } while (0)

    // prologue: prefetch xg for t=0
    unsigned short xgr[4][4];
#pragma unroll
    for (int r = 0; r < 4; ++r) {
        const size_t xoff = ((size_t)(m0 + r) * T_ + 0) * G_ + hc;
#pragma unroll
        for (int q = 0; q < 4; ++q) xgr[r][q] = xg[xoff + q * 1024];
    }
    asm volatile("" ::: "memory");

    for (int t = 0; t < T_; ++t) {
        const unsigned char* h_in = h8 + (size_t)t * (B_ * H_);
        unsigned char* h_out = (unsigned char*)h8 + (size_t)(t + 1) * (B_ * H_);
        const unsigned char* arow8 = h_in + (size_t)arow_i * H_ + g * 8;

        // A-fragment pipeline: plain cached loads, 8-deep double buffer
        f32x4 acc[4] = {};
        long A0[8], A1[8];
        LOADS(A0, 0);
        DRAIN();
        LOADS(A1, 8);
        MFMAS(A0, 0);
        DRAIN();
        LOADS(A0, 16);
        MFMAS(A1, 8);
        DRAIN();
        LOADS(A1, 24);
        MFMAS(A0, 16);
        DRAIN();
        MFMAS(A1, 24);

        // pointwise + masked update; lane owns rows m0..m0+3 x col hc
        float hsv[4], csv[4];
#pragma unroll
        for (int r = 0; r < 4; ++r) {
            const int m = m0 + r;
            float ig = sigmoid_f(acc[0][r] + bv[0] + bf2f(xgr[r][0]));
            float fg = sigmoid_f(acc[1][r] + bv[1] + bf2f(xgr[r][1]));
            float gg = tanh_f(acc[2][r] + bv[2] + bf2f(xgr[r][2]));
            float og = sigmoid_f(acc[3][r] + bv[3] + bf2f(xgr[r][3]));
            float cn = fg * creg[r] + ig * gg;
            float hn = og * tanh_f(cn);
            bool valid = t < sl[r];
            if (valid) { creg[r] = cn; hreg[r] = hn; }
            hsv[r] = valid ? hn : 0.0f;
            csv[r] = valid ? cn : 0.0f;
            STBYTEC(h_out + (size_t)m * H_ + hc, f2fp8(hreg[r]));
        }

        // publish h_out (only the 4 write-through fp8 stores pending)
        DRAIN();
        __syncthreads();      // whole WG published
        const unsigned int tp1 = (unsigned int)(t + 1);
        if (tid == 0) {
            STDWC(flags + wg, tp1);
        }

        // off-critical-path: hs/cs outputs for this step
#pragma unroll
        for (int r = 0; r < 4; ++r) {
            const size_t ooff = ((size_t)(m0 + r) * T_ + t) * H_ + hc;
            __builtin_nontemporal_store(hsv[r], &hs[ooff]);
            __builtin_nontemporal_store(csv[r], &cs[ooff]);
        }

        if (t < T_ - 1) {
            // prefetch next step's xg under the barrier wait
#pragma unroll
            for (int r = 0; r < 4; ++r) {
                const size_t xoff = ((size_t)(m0 + r) * T_ + (t + 1)) * G_ + hc;
#pragma unroll
                for (int q = 0; q < 4; ++q) xgr[r][q] = xg[xoff + q * 1024];
            }
            asm volatile("" ::: "memory");
            if (tid < 64) {   // lane i waits for producer WG rb + 4*i
                while (ld_u32_cohere(fp) < tp1) __builtin_amdgcn_s_sleep(1);
            }
            __syncthreads();
        }
    }
#undef LOADS
#undef MFMAS

    // final bf16 h for k_final (exact fp32 state, written once)
#pragma unroll
    for (int r = 0; r < 4; ++r)
        hb[(size_t)(m0 + r) * H_ + hc] = f2bf(hreg[r]);
}

// ---------------------------------------------------------------------------
// final_hidden[B][H] = tanh(h_last @ aff_w + aff_b)   (unchanged)
__global__ __launch_bounds__(256) void k_final(const unsigned short* __restrict__ h,
                                               const unsigned short* __restrict__ wT,
                                               const float* __restrict__ bias,
                                               float* __restrict__ fin) {
    const int rb = blockIdx.x & 3;
    const int nb = blockIdx.x >> 2;
    const int tid = threadIdx.x;
    const int w = tid >> 6;
    const int l = tid & 63;
    const int g = l >> 4, li = l & 15;

    __shared__ unsigned short As[64][40];
    __shared__ unsigned short Bs[64][40];

    const int srow = tid >> 2;
    const int scol = (tid & 3) * 8;
    const unsigned short* aptr = h + (size_t)(rb * 64 + srow) * H_ + scol;
    const unsigned short* bptr = wT + (size_t)(nb * 64 + srow) * H_ + scol;

    f32x4 acc[4] = {};
    int4 ra = *(const int4*)aptr;
    int4 rb2 = *(const int4*)bptr;
    for (int kk = 0; kk < H_; kk += 32) {
        *(int4*)&As[srow][scol] = ra;
        *(int4*)&Bs[srow][scol] = rb2;
        __syncthreads();
        if (kk + 32 < H_) {
            ra = *(const int4*)(aptr + kk + 32);
            rb2 = *(const int4*)(bptr + kk + 32);
        }
        short8 af = *(const short8*)&As[w * 16 + li][g * 8];
#pragma unroll
        for (int q = 0; q < 4; ++q) {
            short8 bf = *(const short8*)&Bs[q * 16 + li][g * 8];
            acc[q] = __builtin_amdgcn_mfma_f32_16x16x32_bf16(af, bf, acc[q], 0, 0, 0);
        }
        __syncthreads();
    }
    const int m0 = rb * 64 + w * 16 + g * 4;
#pragma unroll
    for (int q = 0; q < 4; ++q) {
        int col = nb * 64 + q * 16 + li;
        float bv = bias[col];
#pragma unroll
        for (int r = 0; r < 4; ++r)
            fin[(size_t)(m0 + r) * H_ + col] = tanh_f(acc[q][r] + bv);
    }
}

// ---------------------------------------------------------------------------
__global__ __launch_bounds__(256) void k_mask(const int* __restrict__ seq_len,
                                              float* __restrict__ mask) {
    int i = blockIdx.x * 256 + threadIdx.x;
    int b = i >> 6, t = i & 63;
    mask[i] = (t < seq_len[b]) ? 1.0f : 0.0f;
}

// ---------------------------------------------------------------------------
extern "C" void kernel_launch(void* const* d_in, const int* in_sizes, int n_in,
                              void* d_out, int out_size, void* d_ws, size_t ws_size,
                              hipStream_t stream) {
    const int* seq = (const int*)d_in[0];
    const int* seq_len = (const int*)d_in[1];
    const float* embed = (const float*)d_in[2];
    const float* x2h_w = (const float*)d_in[3];
    const float* x2h_b = (const float*)d_in[4];
    const float* h2h_w = (const float*)d_in[5];
    const float* h2h_b = (const float*)d_in[6];
    const float* aff_w = (const float*)d_in[7];
    const float* aff_b = (const float*)d_in[8];

    float* out = (float*)d_out;
    float* hs = out;
    float* cs = out + (size_t)B_ * T_ * H_;
    float* fin = cs + (size_t)B_ * T_ * H_;
    float* mask = fin + (size_t)B_ * H_;

    char* p = (char*)d_ws;
    unsigned char*  emb8  = (unsigned char*)p;  p += (size_t)V_ * E_;            // 5.12 MB
    unsigned char*  x2h_8 = (unsigned char*)p;  p += (size_t)G_ * E_;            // 2 MB
    unsigned char*  h2h_8 = (unsigned char*)p;  p += (size_t)G_ * H_;            // 4.2 MB
    unsigned short* aff_t = (unsigned short*)p; p += (size_t)H_ * H_ * 2;        // 2 MB
    unsigned short* xg    = (unsigned short*)p; p += (size_t)B_ * T_ * G_ * 2;   // 128 MB
    unsigned char*  h8    = (unsigned char*)p;  p += (size_t)(T_ + 1) * B_ * H_; // 16.6 MB
    unsigned short* hbuf  = (unsigned short*)p; p += (size_t)B_ * H_ * 2;
    unsigned int*   flags = (unsigned int*)p;   p += NWG_ * sizeof(unsigned int);

    // 1) precompute fp8 operands (embed direct-convert; x2h/h2h direct transpose)
    hipLaunchKernelGGL(k_cvt8f, dim3((V_ * E_ / 4 + 255) / 256), dim3(256), 0, stream,
                       embed, emb8, V_ * E_ / 4);
    hipLaunchKernelGGL(k_transpose8, dim3((E_ / 32) * (G_ / 32)), dim3(256), 0, stream,
                       x2h_w, x2h_8, E_, G_);
    hipLaunchKernelGGL(k_transpose8, dim3((H_ / 32) * (G_ / 32)), dim3(256), 0, stream,
                       h2h_w, h2h_8, H_, G_);
    hipLaunchKernelGGL(k_transpose, dim3((H_ / 32) * (H_ / 32)), dim3(256), 0, stream,
                       aff_w, aff_t, H_, H_);

    // 2) xg = fp8(embed[seq]) @ fp8(x2h_w) + b   (fp32 accum, bf16 out)
    hipLaunchKernelGGL(k_xg, dim3(128 * 32), dim3(256), 0, stream,
                       seq, emb8, x2h_8, x2h_b, xg);

    // 3) zero h8[0] (t=0 input) + flags (every launch)
    hipMemsetAsync(h8, 0, (size_t)B_ * H_, stream);
    hipMemsetAsync(flags, 0, NWG_ * sizeof(unsigned int), stream);

    // 4) persistent cooperative recurrence (r17 structure, unchanged)
    {
        const unsigned short* xg_p = xg;
        const unsigned char* wT8_p = h2h_8;
        const float* b_p = h2h_b;
        const int* sl_p = seq_len;
        unsigned char* h8_p = h8;
        unsigned short* hb_p = hbuf;
        float* hs_p = hs;
        float* cs_p = cs;
        unsigned int* fl_p = flags;
        void* args[] = {(void*)&xg_p, (void*)&wT8_p, (void*)&b_p, (void*)&sl_p,
                        (void*)&h8_p, (void*)&hb_p,
                        (void*)&hs_p, (void*)&cs_p, (void*)&fl_p};
        hipLaunchCooperativeKernel(reinterpret_cast<void*>(k_rnn), dim3(NWG_), dim3(256),
                                   args, 0, stream);
    }

    // 5) final affine (bf16 h written once by k_rnn epilogue) + mask
    hipLaunchKernelGGL(k_final, dim3(64), dim3(256), 0, stream, hbuf, aff_t, aff_b, fin);
    hipLaunchKernelGGL(k_mask, dim3(B_ * T_ / 256), dim3(256), 0, stream, seq_len, mask);
}